// Round 1
// 523.851 us; speedup vs baseline: 1.0384x; 1.0384x over previous
//
#include <hip/hip_runtime.h>
#include <math.h>

// B=8, T_OUT=2048, T_IN=2048, D=512
// attn = softmax(outp @ ctx^T); mix = attn @ ctx; out = tanh([mix,outp] @ W^T + b)
// d_out = out (8.4M f32) ++ attn (33.6M f32)
//
// bf16 hi/lo split-MFMA emulation of f32 GEMMs (no fp32 MFMA on CDNA4).
// This round: scores rewritten as 256x256-tile, 4-phase counted-vmcnt schedule
// (T2 LDS chunk-swizzle + T3/T4 phased counted vmcnt + T5 setprio), 8 waves,
// 128 KiB LDS double buffer. pv/linear unchanged for clean A/B.

typedef short s8v __attribute__((ext_vector_type(8)));    // 8 bf16 (4 VGPR)
typedef float f4v __attribute__((ext_vector_type(4)));    // MFMA acc

__device__ __forceinline__ unsigned short f2bf(float f) {
    unsigned int u = __float_as_uint(f);
    u += 0x7fff + ((u >> 16) & 1);           // RNE
    return (unsigned short)(u >> 16);
}
__device__ __forceinline__ float bf2f(unsigned short h) {
    return __uint_as_float(((unsigned int)h) << 16);
}

__device__ __forceinline__ void async16(void* lds, const void* g) {
    __builtin_amdgcn_global_load_lds(
        (const __attribute__((address_space(1))) unsigned int*)g,
        (__attribute__((address_space(3))) unsigned int*)lds, 16, 0, 0);
}

__device__ __forceinline__ void phase_barrier() {
    asm volatile("" ::: "memory");
    __builtin_amdgcn_s_barrier();
    asm volatile("" ::: "memory");
}

// ---------------------------------------------------------------------------
// Prep: elementwise f32 -> bf16 hi/lo split
// ---------------------------------------------------------------------------
__global__ __launch_bounds__(256) void split_kernel(
    const float* __restrict__ src, unsigned short* __restrict__ hi,
    unsigned short* __restrict__ lo)
{
    const size_t i = ((size_t)blockIdx.x * 256 + threadIdx.x) * 4;
    float4 v = *(const float4*)(src + i);
    ushort4 h, l;
    h.x = f2bf(v.x); l.x = f2bf(v.x - bf2f(h.x));
    h.y = f2bf(v.y); l.y = f2bf(v.y - bf2f(h.y));
    h.z = f2bf(v.z); l.z = f2bf(v.z - bf2f(h.z));
    h.w = f2bf(v.w); l.w = f2bf(v.w - bf2f(h.w));
    *(ushort4*)(hi + i) = h;
    *(ushort4*)(lo + i) = l;
}

// ---------------------------------------------------------------------------
// Prep: ctx[b][i][d] f32 -> ctxT_hi/lo[b][d][i] bf16
// ---------------------------------------------------------------------------
__global__ __launch_bounds__(256) void transpose_split_kernel(
    const float* __restrict__ ctx, unsigned short* __restrict__ tHi,
    unsigned short* __restrict__ tLo)
{
    __shared__ float tile[32][33];
    const int b = blockIdx.z, i0 = blockIdx.y * 32, d0 = blockIdx.x * 32;
    const int t = threadIdx.x;
    {
        const int il = t >> 3, d4 = t & 7;
        float4 v = *(const float4*)(ctx + ((size_t)b * 2048 + i0 + il) * 512 + d0 + d4 * 4);
        tile[il][d4 * 4 + 0] = v.x; tile[il][d4 * 4 + 1] = v.y;
        tile[il][d4 * 4 + 2] = v.z; tile[il][d4 * 4 + 3] = v.w;
    }
    __syncthreads();
    {
        const int dl = t >> 3, i4 = t & 7;
        ushort4 h, l;
        float v0 = tile[i4 * 4 + 0][dl], v1 = tile[i4 * 4 + 1][dl];
        float v2 = tile[i4 * 4 + 2][dl], v3 = tile[i4 * 4 + 3][dl];
        h.x = f2bf(v0); l.x = f2bf(v0 - bf2f(h.x));
        h.y = f2bf(v1); l.y = f2bf(v1 - bf2f(h.y));
        h.z = f2bf(v2); l.z = f2bf(v2 - bf2f(h.z));
        h.w = f2bf(v3); l.w = f2bf(v3 - bf2f(h.w));
        const size_t o = ((size_t)b * 512 + d0 + dl) * 2048 + i0 + i4 * 4;
        *(ushort4*)(tHi + o) = h;
        *(ushort4*)(tLo + o) = l;
    }
}

// ---------------------------------------------------------------------------
// Scores v2: 256x256 tile, BK=32, 8 waves (2x4), split-3 MFMA.
// 4 phases / K-step, counted vmcnt(8), LDS chunk-swizzle, setprio.
// LDS layout per buffer (shorts): Ah@0, Al@8192, Bh@16384, Bl@24576,
// each [256 rows][32 shorts]; chunk' = chunk ^ row[2:1] (16B chunks).
// Grid: 512 blocks (b = id&7 XCD pin, ix inner for A-panel L2 reuse).
// ---------------------------------------------------------------------------
__global__ __launch_bounds__(512, 2) void scores_mfma8(
    const unsigned short* __restrict__ Agh, const unsigned short* __restrict__ Agl,
    const unsigned short* __restrict__ Bgh, const unsigned short* __restrict__ Bgl,
    float* __restrict__ attn)
{
    __shared__ __attribute__((aligned(16))) unsigned short S[65536];  // 128 KiB

    const int id = blockIdx.x;
    const int b = id & 7, seq = id >> 3;
    const int ix = seq & 7, oy = seq >> 3;
    const int tid = threadIdx.x;
    const int wave = tid >> 6, lane = tid & 63;
    const int wr = wave >> 2, wc = wave & 3;       // wave tile: rows wr*128, cols wc*64
    const int c16 = lane & 15;
    // swizzled read chunk: q ^ row[2:1]  (row[2:1] == c16[2:1] since tile rows are 16-aligned)
    const int sq8 = (((lane >> 4) ^ ((c16 >> 1) & 3)) << 3);
    const int aBase = (wr * 128 + c16) * 32 + sq8;
    const int bBase = (wc * 64 + c16) * 32 + sq8;

    // staging: per issue, 512 threads cover 128 rows x 32 shorts (8 KB)
    const int srow = lane >> 2;
    const int kswz = (((lane & 3) ^ ((lane >> 3) & 3)) << 3);   // pre-swizzled source chunk
    const int ldsW = wave * 512;                                 // wave*16 rows * 32 shorts
    const size_t gA = (size_t)(b * 2048 + oy * 256 + wave * 16 + srow) * 512 + kswz;
    const size_t gB = (size_t)(b * 2048 + ix * 256 + wave * 16 + srow) * 512 + kswz;

    auto stageB = [&](int s) {
        unsigned short* D = &S[(s & 1) << 15];
        const int kks = s << 5;
        async16(&D[16384 + ldsW], Bgh + gB + kks);
        async16(&D[20480 + ldsW], Bgh + gB + 65536 + kks);
        async16(&D[24576 + ldsW], Bgl + gB + kks);
        async16(&D[28672 + ldsW], Bgl + gB + 65536 + kks);
    };
    auto stageA = [&](int s) {
        unsigned short* D = &S[(s & 1) << 15];
        const int kks = s << 5;
        async16(&D[0 + ldsW],     Agh + gA + kks);
        async16(&D[4096 + ldsW],  Agh + gA + 65536 + kks);
        async16(&D[8192 + ldsW],  Agl + gA + kks);
        async16(&D[12288 + ldsW], Agl + gA + 65536 + kks);
    };

    f4v acc[8][4];
#pragma unroll
    for (int i = 0; i < 8; ++i)
#pragma unroll
        for (int j = 0; j < 4; ++j) acc[i][j] = (f4v)0.0f;

    // prologue: stage K-steps 0 and 1; wait step 0 (8 newest = step 1 stay in flight)
    stageB(0); stageA(0);
    stageB(1); stageA(1);
    asm volatile("s_waitcnt vmcnt(8)" ::: "memory");
    phase_barrier();

    for (int t = 0; t < 16; ++t) {
        const unsigned short* Sb = &S[(t & 1) << 15];
        s8v ah[4], al[4], bh[4], bl[4];

        // ---- P0: read ALL B frags + first-half A frags; MFMA m0..3 x n0..1
#pragma unroll
        for (int n = 0; n < 4; ++n) {
            bh[n] = *(const s8v*)&Sb[16384 + bBase + n * 512];
            bl[n] = *(const s8v*)&Sb[24576 + bBase + n * 512];
        }
#pragma unroll
        for (int m = 0; m < 4; ++m) {
            ah[m] = *(const s8v*)&Sb[aBase + m * 512];
            al[m] = *(const s8v*)&Sb[8192 + aBase + m * 512];
        }
        phase_barrier();
        __builtin_amdgcn_s_setprio(1);
#pragma unroll
        for (int m = 0; m < 4; ++m)
#pragma unroll
            for (int n = 0; n < 2; ++n) {
                acc[m][n] = __builtin_amdgcn_mfma_f32_16x16x32_bf16(ah[m], bh[n], acc[m][n], 0, 0, 0);
                acc[m][n] = __builtin_amdgcn_mfma_f32_16x16x32_bf16(ah[m], bl[n], acc[m][n], 0, 0, 0);
                acc[m][n] = __builtin_amdgcn_mfma_f32_16x16x32_bf16(al[m], bh[n], acc[m][n], 0, 0, 0);
            }
        __builtin_amdgcn_s_setprio(0);
        phase_barrier();

        // ---- P1: stage B(t+2) (B fully consumed in P0); MFMA m0..3 x n2..3
        if (t < 14) stageB(t + 2);
        phase_barrier();
        __builtin_amdgcn_s_setprio(1);
#pragma unroll
        for (int m = 0; m < 4; ++m)
#pragma unroll
            for (int n = 2; n < 4; ++n) {
                acc[m][n] = __builtin_amdgcn_mfma_f32_16x16x32_bf16(ah[m], bh[n], acc[m][n], 0, 0, 0);
                acc[m][n] = __builtin_amdgcn_mfma_f32_16x16x32_bf16(ah[m], bl[n], acc[m][n], 0, 0, 0);
                acc[m][n] = __builtin_amdgcn_mfma_f32_16x16x32_bf16(al[m], bh[n], acc[m][n], 0, 0, 0);
            }
        __builtin_amdgcn_s_setprio(0);
        phase_barrier();

        // ---- P2: read second-half A frags; MFMA m4..7 x n0..1
#pragma unroll
        for (int m = 0; m < 4; ++m) {
            ah[m] = *(const s8v*)&Sb[aBase + 2048 + m * 512];
            al[m] = *(const s8v*)&Sb[8192 + aBase + 2048 + m * 512];
        }
        phase_barrier();
        __builtin_amdgcn_s_setprio(1);
#pragma unroll
        for (int m = 0; m < 4; ++m)
#pragma unroll
            for (int n = 0; n < 2; ++n) {
                acc[m + 4][n] = __builtin_amdgcn_mfma_f32_16x16x32_bf16(ah[m], bh[n], acc[m + 4][n], 0, 0, 0);
                acc[m + 4][n] = __builtin_amdgcn_mfma_f32_16x16x32_bf16(ah[m], bl[n], acc[m + 4][n], 0, 0, 0);
                acc[m + 4][n] = __builtin_amdgcn_mfma_f32_16x16x32_bf16(al[m], bh[n], acc[m + 4][n], 0, 0, 0);
            }
        __builtin_amdgcn_s_setprio(0);
        phase_barrier();

        // ---- P3: stage A(t+2) (A fully consumed by end of P2); MFMA m4..7 x n2..3
        if (t < 14) stageA(t + 2);
        phase_barrier();
        __builtin_amdgcn_s_setprio(1);
#pragma unroll
        for (int m = 0; m < 4; ++m)
#pragma unroll
            for (int n = 2; n < 4; ++n) {
                acc[m + 4][n] = __builtin_amdgcn_mfma_f32_16x16x32_bf16(ah[m], bh[n], acc[m + 4][n], 0, 0, 0);
                acc[m + 4][n] = __builtin_amdgcn_mfma_f32_16x16x32_bf16(ah[m], bl[n], acc[m + 4][n], 0, 0, 0);
                acc[m + 4][n] = __builtin_amdgcn_mfma_f32_16x16x32_bf16(al[m], bh[n], acc[m + 4][n], 0, 0, 0);
            }
        __builtin_amdgcn_s_setprio(0);
        // counted wait for next K-step's staged data; never 0 in steady state
        if (t < 14) {
            asm volatile("s_waitcnt vmcnt(8)" ::: "memory");
        } else if (t == 14) {
            asm volatile("s_waitcnt vmcnt(0)" ::: "memory");
        }
        phase_barrier();
    }

    float* dst = attn + ((size_t)(b * 2048 + oy * 256 + wr * 128)) * 2048 + ix * 256 + wc * 64;
    const int q4 = (lane >> 4) * 4;
#pragma unroll
    for (int mt = 0; mt < 8; ++mt)
#pragma unroll
        for (int nt = 0; nt < 4; ++nt)
#pragma unroll
            for (int r = 0; r < 4; ++r)
                dst[(size_t)(mt * 16 + q4 + r) * 2048 + nt * 16 + c16] = acc[mt][nt][r];
}

// ---------------------------------------------------------------------------
// Softmax: in-place; optionally emits bf16 copy of the final probabilities.
// ---------------------------------------------------------------------------
__global__ __launch_bounds__(256) void softmax_kernel(
    float* __restrict__ attn, unsigned short* __restrict__ attn_bf)
{
    const size_t base = (size_t)blockIdx.x * 2048;
    const int tid = threadIdx.x;
    float4 v0 = *(float4*)(attn + base + tid * 4);
    float4 v1 = *(float4*)(attn + base + 1024 + tid * 4);

    float mx = fmaxf(fmaxf(fmaxf(v0.x, v0.y), fmaxf(v0.z, v0.w)),
                     fmaxf(fmaxf(v1.x, v1.y), fmaxf(v1.z, v1.w)));
#pragma unroll
    for (int off = 32; off > 0; off >>= 1) mx = fmaxf(mx, __shfl_down(mx, off));

    __shared__ float red[4];
    const int wave = tid >> 6, lane = tid & 63;
    if (lane == 0) red[wave] = mx;
    __syncthreads();
    if (tid == 0) red[0] = fmaxf(fmaxf(red[0], red[1]), fmaxf(red[2], red[3]));
    __syncthreads();
    mx = red[0];
    __syncthreads();

    v0.x = expf(v0.x - mx); v0.y = expf(v0.y - mx);
    v0.z = expf(v0.z - mx); v0.w = expf(v0.w - mx);
    v1.x = expf(v1.x - mx); v1.y = expf(v1.y - mx);
    v1.z = expf(v1.z - mx); v1.w = expf(v1.w - mx);

    float s = v0.x + v0.y + v0.z + v0.w + v1.x + v1.y + v1.z + v1.w;
#pragma unroll
    for (int off = 32; off > 0; off >>= 1) s += __shfl_down(s, off);
    if (lane == 0) red[wave] = s;
    __syncthreads();
    if (tid == 0) red[0] = red[0] + red[1] + red[2] + red[3];
    __syncthreads();
    const float inv = 1.0f / red[0];

    v0.x *= inv; v0.y *= inv; v0.z *= inv; v0.w *= inv;
    v1.x *= inv; v1.y *= inv; v1.z *= inv; v1.w *= inv;
    *(float4*)(attn + base + tid * 4) = v0;
    *(float4*)(attn + base + 1024 + tid * 4) = v1;

    if (attn_bf) {
        ushort4 h0, h1;
        h0.x = f2bf(v0.x); h0.y = f2bf(v0.y); h0.z = f2bf(v0.z); h0.w = f2bf(v0.w);
        h1.x = f2bf(v1.x); h1.y = f2bf(v1.y); h1.z = f2bf(v1.z); h1.w = f2bf(v1.w);
        *(ushort4*)(attn_bf + base + tid * 4) = h0;
        *(ushort4*)(attn_bf + base + 1024 + tid * 4) = h1;
    }
}

// ---------------------------------------------------------------------------
// PV tier-1: A = attn_bf (async staged), B = ctxT hi/lo (2 MFMA).
// 1D grid 512: b=id&7, nx inner. Writes mix as bf16 hi/lo.
// ---------------------------------------------------------------------------
__global__ __launch_bounds__(256) void pv_mfma_bf(
    const unsigned short* __restrict__ attn_bf,
    const unsigned short* __restrict__ Bgh, const unsigned short* __restrict__ Bgl,
    unsigned short* __restrict__ mixHi, unsigned short* __restrict__ mixLo)
{
    __shared__ __attribute__((aligned(16))) unsigned short Ab[128 * 32],
                                                           Bh[128 * 32], Bl[128 * 32];
    const int id = blockIdx.x;
    const int b = id & 7, seq = id >> 3;
    const int nx = seq & 3, my = seq >> 2;
    const int tid = threadIdx.x, wave = tid >> 6, lane = tid & 63;
    const int wm = wave >> 1, wn = wave & 1;
    const int c16 = lane & 15, q8 = (lane >> 4) * 8;

    const size_t arow = (size_t)(b * 2048 + my * 128);
    const size_t brow = (size_t)(b * 512 + nx * 128);

    f4v acc[4][4];
#pragma unroll
    for (int i = 0; i < 4; ++i)
#pragma unroll
        for (int j = 0; j < 4; ++j) acc[i][j] = (f4v)0.0f;

    for (int kk = 0; kk < 2048; kk += 32) {
#pragma unroll
        for (int it = 0; it < 2; ++it) {
            const int r0 = it * 64 + wave * 16;
            const int rr = r0 + (lane >> 2);
            const size_t ga = (arow + rr) * 2048 + kk + (lane & 3) * 8;
            const size_t gb = (brow + rr) * 2048 + kk + (lane & 3) * 8;
            async16(&Ab[r0 * 32], attn_bf + ga);
            async16(&Bh[r0 * 32], Bgh + gb);
            async16(&Bl[r0 * 32], Bgl + gb);
        }
        __syncthreads();
        s8v ab[4], bh[4], bl[4];
#pragma unroll
        for (int t = 0; t < 4; ++t) {
            ab[t] = *(const s8v*)&Ab[(wm * 64 + t * 16 + c16) * 32 + q8];
            bh[t] = *(const s8v*)&Bh[(wn * 64 + t * 16 + c16) * 32 + q8];
            bl[t] = *(const s8v*)&Bl[(wn * 64 + t * 16 + c16) * 32 + q8];
        }
#pragma unroll
        for (int mt = 0; mt < 4; ++mt)
#pragma unroll
            for (int nt = 0; nt < 4; ++nt) {
                acc[mt][nt] = __builtin_amdgcn_mfma_f32_16x16x32_bf16(ab[mt], bh[nt], acc[mt][nt], 0, 0, 0);
                acc[mt][nt] = __builtin_amdgcn_mfma_f32_16x16x32_bf16(ab[mt], bl[nt], acc[mt][nt], 0, 0, 0);
            }
        __syncthreads();
    }
    const int q4 = (lane >> 4) * 4;
    const size_t mrow = (size_t)(b * 2048 + my * 128 + wm * 64);
#pragma unroll
    for (int mt = 0; mt < 4; ++mt)
#pragma unroll
        for (int nt = 0; nt < 4; ++nt) {
            const int col = nx * 128 + wn * 64 + nt * 16 + c16;
#pragma unroll
            for (int r = 0; r < 4; ++r) {
                float v = acc[mt][nt][r];
                unsigned short h = f2bf(v);
                unsigned short l = f2bf(v - bf2f(h));
                const size_t o = (mrow + mt * 16 + q4 + r) * 512 + col;
                mixHi[o] = h; mixLo[o] = l;
            }
        }
}

// ---------------------------------------------------------------------------
// PV tier-2 (round-1 structure + swizzle): A = f32 attn converted inline.
// ---------------------------------------------------------------------------
__global__ __launch_bounds__(256) void pv_mfma_cvt(
    const float* __restrict__ attn,
    const unsigned short* __restrict__ Bgh, const unsigned short* __restrict__ Bgl,
    unsigned short* __restrict__ mixHi, unsigned short* __restrict__ mixLo)
{
    __shared__ __attribute__((aligned(16))) unsigned short Ab[128 * 32],
                                                           Bh[128 * 32], Bl[128 * 32];
    const int id = blockIdx.x;
    const int b = id & 7, seq = id >> 3;
    const int nx = seq & 3, my = seq >> 2;
    const int tid = threadIdx.x, wave = tid >> 6, lane = tid & 63;
    const int wm = wave >> 1, wn = wave & 1;
    const int c16 = lane & 15, q8 = (lane >> 4) * 8;

    const float* Abase = attn + ((size_t)b * 2048 + my * 128) * 2048;
    const size_t brow = (size_t)(b * 512 + nx * 128);

    f4v acc[4][4];
#pragma unroll
    for (int i = 0; i < 4; ++i)
#pragma unroll
        for (int j = 0; j < 4; ++j) acc[i][j] = (f4v)0.0f;

    for (int kk = 0; kk < 2048; kk += 32) {
#pragma unroll
        for (int it = 0; it < 4; ++it) {
            const int idx = tid + it * 256;
            const int r = idx >> 3, kc = idx & 7;
            float4 v = *(const float4*)(Abase + (size_t)r * 2048 + kk + kc * 4);
            ushort4 h;
            h.x = f2bf(v.x); h.y = f2bf(v.y); h.z = f2bf(v.z); h.w = f2bf(v.w);
            *(ushort4*)&Ab[r * 32 + kc * 4] = h;
        }
#pragma unroll
        for (int it = 0; it < 2; ++it) {
            const int r0 = it * 64 + wave * 16;
            const size_t gb = (brow + r0 + (lane >> 2)) * 2048 + kk + (lane & 3) * 8;
            async16(&Bh[r0 * 32], Bgh + gb);
            async16(&Bl[r0 * 32], Bgl + gb);
        }
        __syncthreads();
        s8v ab[4], bh[4], bl[4];
#pragma unroll
        for (int t = 0; t < 4; ++t) {
            ab[t] = *(const s8v*)&Ab[(wm * 64 + t * 16 + c16) * 32 + q8];
            bh[t] = *(const s8v*)&Bh[(wn * 64 + t * 16 + c16) * 32 + q8];
            bl[t] = *(const s8v*)&Bl[(wn * 64 + t * 16 + c16) * 32 + q8];
        }
#pragma unroll
        for (int mt = 0; mt < 4; ++mt)
#pragma unroll
            for (int nt = 0; nt < 4; ++nt) {
                acc[mt][nt] = __builtin_amdgcn_mfma_f32_16x16x32_bf16(ab[mt], bh[nt], acc[mt][nt], 0, 0, 0);
                acc[mt][nt] = __builtin_amdgcn_mfma_f32_16x16x32_bf16(ab[mt], bl[nt], acc[mt][nt], 0, 0, 0);
            }
        __syncthreads();
    }
    const int q4 = (lane >> 4) * 4;
    const size_t mrow = (size_t)(b * 2048 + my * 128 + wm * 64);
#pragma unroll
    for (int mt = 0; mt < 4; ++mt)
#pragma unroll
        for (int nt = 0; nt < 4; ++nt) {
            const int col = nx * 128 + wn * 64 + nt * 16 + c16;
#pragma unroll
            for (int r = 0; r < 4; ++r) {
                float v = acc[mt][nt][r];
                unsigned short h = f2bf(v);
                unsigned short l = f2bf(v - bf2f(h));
                const size_t o = (mrow + mt * 16 + q4 + r) * 512 + col;
                mixHi[o] = h; mixLo[o] = l;
            }
        }
}

// ---------------------------------------------------------------------------
// Linear: full split-3, fused bias+tanh. 1D grid 512:
// xcd=id&7 -> my%8, nx inner per-XCD (A tile fetched once, W set L2-resident)
// ---------------------------------------------------------------------------
__global__ __launch_bounds__(256) void linear_mfma(
    const unsigned short* __restrict__ mixHi, const unsigned short* __restrict__ mixLo,
    const unsigned short* __restrict__ outHi, const unsigned short* __restrict__ outLo,
    const unsigned short* __restrict__ Wh, const unsigned short* __restrict__ Wl,
    const float* __restrict__ bias, float* __restrict__ dst)
{
    __shared__ __attribute__((aligned(16))) unsigned short Ah[128 * 32], Al[128 * 32],
                                                           Bh[128 * 32], Bl[128 * 32];
    const int id = blockIdx.x;
    const int xcd = id & 7, seq = id >> 3;
    const int nx = seq & 3;
    const int my = (seq >> 2) * 8 + xcd;
    const int tid = threadIdx.x, wave = tid >> 6, lane = tid & 63;
    const int wm = wave >> 1, wn = wave & 1;
    const int c16 = lane & 15, q8 = (lane >> 4) * 8;

    f4v acc[4][4];
#pragma unroll
    for (int i = 0; i < 4; ++i)
#pragma unroll
        for (int j = 0; j < 4; ++j) acc[i][j] = (f4v)0.0f;

    for (int kk = 0; kk < 1024; kk += 32) {
        const unsigned short* ah_src = (kk < 512) ? mixHi : outHi;
        const unsigned short* al_src = (kk < 512) ? mixLo : outLo;
        const int kc0 = (kk < 512) ? kk : kk - 512;
#pragma unroll
        for (int it = 0; it < 2; ++it) {
            const int r0 = it * 64 + wave * 16;
            const size_t ga = (size_t)(my * 128 + r0 + (lane >> 2)) * 512 + kc0 + (lane & 3) * 8;
            const size_t gb = (size_t)(nx * 128 + r0 + (lane >> 2)) * 1024 + kk + (lane & 3) * 8;
            async16(&Ah[r0 * 32], ah_src + ga);
            async16(&Al[r0 * 32], al_src + ga);
            async16(&Bh[r0 * 32], Wh + gb);
            async16(&Bl[r0 * 32], Wl + gb);
        }
        __syncthreads();
        s8v ah[4], al[4], bh[4], bl[4];
#pragma unroll
        for (int t = 0; t < 4; ++t) {
            ah[t] = *(const s8v*)&Ah[(wm * 64 + t * 16 + c16) * 32 + q8];
            al[t] = *(const s8v*)&Al[(wm * 64 + t * 16 + c16) * 32 + q8];
            bh[t] = *(const s8v*)&Bh[(wn * 64 + t * 16 + c16) * 32 + q8];
            bl[t] = *(const s8v*)&Bl[(wn * 64 + t * 16 + c16) * 32 + q8];
        }
#pragma unroll
        for (int mt = 0; mt < 4; ++mt)
#pragma unroll
            for (int nt = 0; nt < 4; ++nt) {
                acc[mt][nt] = __builtin_amdgcn_mfma_f32_16x16x32_bf16(ah[mt], bh[nt], acc[mt][nt], 0, 0, 0);
                acc[mt][nt] = __builtin_amdgcn_mfma_f32_16x16x32_bf16(ah[mt], bl[nt], acc[mt][nt], 0, 0, 0);
                acc[mt][nt] = __builtin_amdgcn_mfma_f32_16x16x32_bf16(al[mt], bh[nt], acc[mt][nt], 0, 0, 0);
            }
        __syncthreads();
    }
    const int q4 = (lane >> 4) * 4;
#pragma unroll
    for (int mt = 0; mt < 4; ++mt)
#pragma unroll
        for (int nt = 0; nt < 4; ++nt) {
            const int col = nx * 128 + wn * 64 + nt * 16 + c16;
            const float bb = bias[col];
#pragma unroll
            for (int r = 0; r < 4; ++r) {
                const size_t row = (size_t)(my * 128 + wm * 64 + mt * 16 + q4 + r);
                dst[row * 512 + col] = tanhf(acc[mt][nt][r] + bb);
            }
        }
}

// ===========================================================================
// Fallback f32 path
// ===========================================================================
#define BK 32
#define PAD 68

__global__ __launch_bounds__(256) void scores_f32(
    const float* __restrict__ outp, const float* __restrict__ ctx,
    float* __restrict__ attn)
{
    __shared__ float As[BK][PAD];
    __shared__ float Bs[BK][PAD];
    const int b = blockIdx.z, oy = blockIdx.y, ix = blockIdx.x;
    const int tid = threadIdx.x;
    const int tx = tid & 15, ty = tid >> 4;
    const float* Abase = outp + ((size_t)b * 2048 + oy * 64) * 512;
    const float* Bbase = ctx  + ((size_t)b * 2048 + ix * 64) * 512;
    float acc[4][4] = {};
    for (int kk = 0; kk < 512; kk += BK) {
#pragma unroll
        for (int h = 0; h < 2; ++h) {
            const int f = tid + h * 256;
            const int row = f >> 3, k4 = f & 7;
            float4 a = *(const float4*)(Abase + (size_t)row * 512 + kk + k4 * 4);
            float4 c = *(const float4*)(Bbase + (size_t)row * 512 + kk + k4 * 4);
            As[k4 * 4 + 0][row] = a.x; As[k4 * 4 + 1][row] = a.y;
            As[k4 * 4 + 2][row] = a.z; As[k4 * 4 + 3][row] = a.w;
            Bs[k4 * 4 + 0][row] = c.x; Bs[k4 * 4 + 1][row] = c.y;
            Bs[k4 * 4 + 2][row] = c.z; Bs[k4 * 4 + 3][row] = c.w;
        }
        __syncthreads();
#pragma unroll
        for (int k = 0; k < BK; ++k) {
            float4 av = *(const float4*)&As[k][ty * 4];
            float4 bv = *(const float4*)&Bs[k][tx * 4];
            acc[0][0] += av.x * bv.x; acc[0][1] += av.x * bv.y; acc[0][2] += av.x * bv.z; acc[0][3] += av.x * bv.w;
            acc[1][0] += av.y * bv.x; acc[1][1] += av.y * bv.y; acc[1][2] += av.y * bv.z; acc[1][3] += av.y * bv.w;
            acc[2][0] += av.z * bv.x; acc[2][1] += av.z * bv.y; acc[2][2] += av.z * bv.z; acc[2][3] += av.z * bv.w;
            acc[3][0] += av.w * bv.x; acc[3][1] += av.w * bv.y; acc[3][2] += av.w * bv.z; acc[3][3] += av.w * bv.w;
        }
        __syncthreads();
    }
    float* dst = attn + ((size_t)b * 2048 + oy * 64 + ty * 4) * 2048 + ix * 64 + tx * 4;
#pragma unroll
    for (int i = 0; i < 4; ++i)
        *(float4*)(dst + (size_t)i * 2048) = make_float4(acc[i][0], acc[i][1], acc[i][2], acc[i][3]);
}

__global__ __launch_bounds__(256) void pv_f32(
    const float* __restrict__ attn, const float* __restrict__ ctx,
    float* __restrict__ mix)
{
    __shared__ float As[BK][PAD];
    __shared__ float Bs[BK][PAD];
    const int b = blockIdx.z, my = blockIdx.y, nx = blockIdx.x;
    const int tid = threadIdx.x;
    const int tx = tid & 15, ty = tid >> 4;
    const float* Abase = attn + ((size_t)b * 2048 + my * 64) * 2048;
    const float* Bbase = ctx  + ((size_t)b * 2048) * 512 + nx * 64;
    float acc[4][4] = {};
    for (int kk = 0; kk < 2048; kk += BK) {
#pragma unroll
        for (int h = 0; h < 2; ++h) {
            const int f = tid + h * 256;
            const int row = f >> 3, k4 = f & 7;
            float4 a = *(const float4*)(Abase + (size_t)row * 2048 + kk + k4 * 4);
            As[k4 * 4 + 0][row] = a.x; As[k4 * 4 + 1][row] = a.y;
            As[k4 * 4 + 2][row] = a.z; As[k4 * 4 + 3][row] = a.w;
            const int krow = f >> 4, col4 = f & 15;
            float4 c = *(const float4*)(Bbase + (size_t)(kk + krow) * 512 + col4 * 4);
            *(float4*)&Bs[krow][col4 * 4] = c;
        }
        __syncthreads();
#pragma unroll
        for (int k = 0; k < BK; ++k) {
            float4 av = *(const float4*)&As[k][ty * 4];
            float4 bv = *(const float4*)&Bs[k][tx * 4];
            acc[0][0] += av.x * bv.x; acc[0][1] += av.x * bv.y; acc[0][2] += av.x * bv.z; acc[0][3] += av.x * bv.w;
            acc[1][0] += av.y * bv.x; acc[1][1] += av.y * bv.y; acc[1][2] += av.y * bv.z; acc[1][3] += av.y * bv.w;
            acc[2][0] += av.z * bv.x; acc[2][1] += av.z * bv.y; acc[2][2] += av.z * bv.z; acc[2][3] += av.z * bv.w;
            acc[3][0] += av.w * bv.x; acc[3][1] += av.w * bv.y; acc[3][2] += av.w * bv.z; acc[3][3] += av.w * bv.w;
        }
        __syncthreads();
    }
    float* dst = mix + ((size_t)b * 2048 + my * 64 + ty * 4) * 512 + nx * 64 + tx * 4;
#pragma unroll
    for (int i = 0; i < 4; ++i)
        *(float4*)(dst + (size_t)i * 512) = make_float4(acc[i][0], acc[i][1], acc[i][2], acc[i][3]);
}

__global__ __launch_bounds__(256) void linear_f32(
    const float* __restrict__ mix, const float* __restrict__ outp,
    const float* __restrict__ Wm, const float* __restrict__ bias,
    float* __restrict__ dst)
{
    __shared__ float As[BK][PAD];
    __shared__ float Ws[BK][PAD];
    const int my = blockIdx.y, nx = blockIdx.x;
    const int tid = threadIdx.x;
    const int tx = tid & 15, ty = tid >> 4;
    const int m0 = my * 64, n0 = nx * 64;
    float acc[4][4] = {};
    for (int kk = 0; kk < 1024; kk += BK) {
        const float* Abase = (kk < 512) ? (mix + (size_t)m0 * 512 + kk)
                                        : (outp + (size_t)m0 * 512 + (kk - 512));
#pragma unroll
        for (int h = 0; h < 2; ++h) {
            const int f = tid + h * 256;
            const int row = f >> 3, k4 = f & 7;
            float4 a = *(const float4*)(Abase + (size_t)row * 512 + k4 * 4);
            As[k4 * 4 + 0][row] = a.x; As[k4 * 4 + 1][row] = a.y;
            As[k4 * 4 + 2][row] = a.z; As[k4 * 4 + 3][row] = a.w;
            float4 w = *(const float4*)(Wm + (size_t)(n0 + row) * 1024 + kk + k4 * 4);
            Ws[k4 * 4 + 0][row] = w.x; Ws[k4 * 4 + 1][row] = w.y;
            Ws[k4 * 4 + 2][row] = w.z; Ws[k4 * 4 + 3][row] = w.w;
        }
        __syncthreads();
#pragma unroll
        for (int k = 0; k < BK; ++k) {
            float4 av = *(const float4*)&As[k][ty * 4];
            float4 bv = *(const float4*)&Ws[k][tx * 4];
            acc[0][0] += av.x * bv.x; acc[0][1] += av.x * bv.y; acc[0][2] += av.x * bv.z; acc[0][3] += av.x * bv.w;
            acc[1][0] += av.y * bv.x; acc[1][1] += av.y * bv.y; acc[1][2] += av.y * bv.z; acc[1][3] += av.y * bv.w;
            acc[2][0] += av.z * bv.x; acc[2][1] += av.z * bv.y; acc[2][2] += av.z * bv.z; acc[2][3] += av.z * bv.w;
            acc[3][0] += av.w * bv.x; acc[3][1] += av.w * bv.y; acc[3][2] += av.w * bv.z; acc[3][3] += av.w * bv.w;
        }
        __syncthreads();
    }
#pragma unroll
    for (int i = 0; i < 4; ++i) {
        const int n = n0 + tx * 4;
        float4 bv = *(const float4*)(bias + n);
        float4 v;
        v.x = tanhf(acc[i][0] + bv.x); v.y = tanhf(acc[i][1] + bv.y);
        v.z = tanhf(acc[i][2] + bv.z); v.w = tanhf(acc[i][3] + bv.w);
        *(float4*)(dst + (size_t)(m0 + ty * 4 + i) * 512 + n) = v;
    }
}

// ===========================================================================
extern "C" void kernel_launch(void* const* d_in, const int* in_sizes, int n_in,
                              void* d_out, int out_size, void* d_ws, size_t ws_size,
                              hipStream_t stream) {
    const float* outp = (const float*)d_in[0];   // [8,2048,512]
    const float* ctx  = (const float*)d_in[1];   // [8,2048,512]
    const float* Wm   = (const float*)d_in[2];   // [512,1024]
    const float* bias = (const float*)d_in[3];   // [512]

    float* out  = (float*)d_out;
    float* attn = out + (size_t)8 * 2048 * 512;

    const size_t MB = 1ull << 20;
    const size_t NEED1 = 162 * MB;   // tier-1: +64MB attn_bf, mix aliases ctx
    const size_t NEED2 = 130 * MB;   // tier-2: round-1 layout

    if (ws_size >= NEED1) {
        char* w = (char*)d_ws;
        unsigned short* outp_hi = (unsigned short*)(w);              // 16MB
        unsigned short* outp_lo = (unsigned short*)(w + 16 * MB);
        unsigned short* ctx_hi  = (unsigned short*)(w + 32 * MB);
        unsigned short* ctx_lo  = (unsigned short*)(w + 48 * MB);
        unsigned short* ctxT_hi = (unsigned short*)(w + 64 * MB);
        unsigned short* ctxT_lo = (unsigned short*)(w + 80 * MB);
        unsigned short* W_hi    = (unsigned short*)(w + 96 * MB);
        unsigned short* W_lo    = (unsigned short*)(w + 97 * MB);
        unsigned short* attn_bf = (unsigned short*)(w + 98 * MB);    // 64MB
        // mix aliases ctx_hi/ctx_lo (ctx dead after scores)
        unsigned short* mix_hi  = ctx_hi;
        unsigned short* mix_lo  = ctx_lo;

        split_kernel<<<dim3(8192), 256, 0, stream>>>(outp, outp_hi, outp_lo);
        split_kernel<<<dim3(8192), 256, 0, stream>>>(ctx, ctx_hi, ctx_lo);
        split_kernel<<<dim3(512), 256, 0, stream>>>(Wm, W_hi, W_lo);
        transpose_split_kernel<<<dim3(16, 64, 8), 256, 0, stream>>>(ctx, ctxT_hi, ctxT_lo);

        scores_mfma8<<<dim3(512), 512, 0, stream>>>(outp_hi, outp_lo, ctx_hi, ctx_lo, attn);
        softmax_kernel<<<dim3(16384), 256, 0, stream>>>(attn, attn_bf);
        pv_mfma_bf<<<dim3(512), 256, 0, stream>>>(attn_bf, ctxT_hi, ctxT_lo, mix_hi, mix_lo);
        linear_mfma<<<dim3(512), 256, 0, stream>>>(mix_hi, mix_lo, outp_hi, outp_lo,
                                                   W_hi, W_lo, bias, out);
    } else if (ws_size >= NEED2) {
        char* w = (char*)d_ws;
        unsigned short* outp_hi = (unsigned short*)(w);
        unsigned short* outp_lo = (unsigned short*)(w + 16 * MB);
        unsigned short* ctx_hi  = (unsigned short*)(w + 32 * MB);
        unsigned short* ctx_lo  = (unsigned short*)(w + 48 * MB);
        unsigned short* ctxT_hi = (unsigned short*)(w + 64 * MB);
        unsigned short* ctxT_lo = (unsigned short*)(w + 80 * MB);
        unsigned short* W_hi    = (unsigned short*)(w + 96 * MB);
        unsigned short* W_lo    = (unsigned short*)(w + 97 * MB);
        unsigned short* mix_hi  = (unsigned short*)(w + 98 * MB);
        unsigned short* mix_lo  = (unsigned short*)(w + 114 * MB);

        split_kernel<<<dim3(8192), 256, 0, stream>>>(outp, outp_hi, outp_lo);
        split_kernel<<<dim3(8192), 256, 0, stream>>>(ctx, ctx_hi, ctx_lo);
        split_kernel<<<dim3(512), 256, 0, stream>>>(Wm, W_hi, W_lo);
        transpose_split_kernel<<<dim3(16, 64, 8), 256, 0, stream>>>(ctx, ctxT_hi, ctxT_lo);

        scores_mfma8<<<dim3(512), 512, 0, stream>>>(outp_hi, outp_lo, ctx_hi, ctx_lo, attn);
        softmax_kernel<<<dim3(16384), 256, 0, stream>>>(attn, nullptr);
        pv_mfma_cvt<<<dim3(512), 256, 0, stream>>>(attn, ctxT_hi, ctxT_lo, mix_hi, mix_lo);
        linear_mfma<<<dim3(512), 256, 0, stream>>>(mix_hi, mix_lo, outp_hi, outp_lo,
                                                   W_hi, W_lo, bias, out);
    } else {
        float* mix = (float*)d_ws;
        scores_f32<<<dim3(32, 32, 8), 256, 0, stream>>>(outp, ctx, attn);
        softmax_kernel<<<dim3(16384), 256, 0, stream>>>(attn, nullptr);
        pv_f32<<<dim3(8, 32, 8), 256, 0, stream>>>(attn, ctx, mix);
        linear_f32<<<dim3(8, 256), 256, 0, stream>>>(mix, outp, Wm, bias, out);
    }
}

// Round 2
// 509.217 us; speedup vs baseline: 1.0682x; 1.0287x over previous
//
#include <hip/hip_runtime.h>
#include <math.h>

// B=8, T_OUT=2048, T_IN=2048, D=512
// attn = softmax(outp @ ctx^T); mix = attn @ ctx; out = tanh([mix,outp] @ W^T + b)
// d_out = out (8.4M f32) ++ attn (33.6M f32)
//
// bf16 hi/lo split-MFMA emulation of f32 GEMMs (no fp32 MFMA on CDNA4).
// Round 2: scores restructured from 4-phase lockstep (8 barriers/K-step,
// reads serialized against MFMA -> MfmaUtil 40%) to 2-barrier overlap
// schedule: B(t) regs held across K-step, A1/B(t+1) ds_reads issued UNDER
// MFMA clusters, counted vmcnt(8), stage-2-ahead. pv/linear unchanged.

typedef short s8v __attribute__((ext_vector_type(8)));    // 8 bf16 (4 VGPR)
typedef float f4v __attribute__((ext_vector_type(4)));    // MFMA acc

__device__ __forceinline__ unsigned short f2bf(float f) {
    unsigned int u = __float_as_uint(f);
    u += 0x7fff + ((u >> 16) & 1);           // RNE
    return (unsigned short)(u >> 16);
}
__device__ __forceinline__ float bf2f(unsigned short h) {
    return __uint_as_float(((unsigned int)h) << 16);
}

__device__ __forceinline__ void async16(void* lds, const void* g) {
    __builtin_amdgcn_global_load_lds(
        (const __attribute__((address_space(1))) unsigned int*)g,
        (__attribute__((address_space(3))) unsigned int*)lds, 16, 0, 0);
}

__device__ __forceinline__ void phase_barrier() {
    asm volatile("" ::: "memory");
    __builtin_amdgcn_s_barrier();
    asm volatile("" ::: "memory");
}

// ---------------------------------------------------------------------------
// Prep: elementwise f32 -> bf16 hi/lo split
// ---------------------------------------------------------------------------
__global__ __launch_bounds__(256) void split_kernel(
    const float* __restrict__ src, unsigned short* __restrict__ hi,
    unsigned short* __restrict__ lo)
{
    const size_t i = ((size_t)blockIdx.x * 256 + threadIdx.x) * 4;
    float4 v = *(const float4*)(src + i);
    ushort4 h, l;
    h.x = f2bf(v.x); l.x = f2bf(v.x - bf2f(h.x));
    h.y = f2bf(v.y); l.y = f2bf(v.y - bf2f(h.y));
    h.z = f2bf(v.z); l.z = f2bf(v.z - bf2f(h.z));
    h.w = f2bf(v.w); l.w = f2bf(v.w - bf2f(h.w));
    *(ushort4*)(hi + i) = h;
    *(ushort4*)(lo + i) = l;
}

// ---------------------------------------------------------------------------
// Prep: ctx[b][i][d] f32 -> ctxT_hi/lo[b][d][i] bf16
// ---------------------------------------------------------------------------
__global__ __launch_bounds__(256) void transpose_split_kernel(
    const float* __restrict__ ctx, unsigned short* __restrict__ tHi,
    unsigned short* __restrict__ tLo)
{
    __shared__ float tile[32][33];
    const int b = blockIdx.z, i0 = blockIdx.y * 32, d0 = blockIdx.x * 32;
    const int t = threadIdx.x;
    {
        const int il = t >> 3, d4 = t & 7;
        float4 v = *(const float4*)(ctx + ((size_t)b * 2048 + i0 + il) * 512 + d0 + d4 * 4);
        tile[il][d4 * 4 + 0] = v.x; tile[il][d4 * 4 + 1] = v.y;
        tile[il][d4 * 4 + 2] = v.z; tile[il][d4 * 4 + 3] = v.w;
    }
    __syncthreads();
    {
        const int dl = t >> 3, i4 = t & 7;
        ushort4 h, l;
        float v0 = tile[i4 * 4 + 0][dl], v1 = tile[i4 * 4 + 1][dl];
        float v2 = tile[i4 * 4 + 2][dl], v3 = tile[i4 * 4 + 3][dl];
        h.x = f2bf(v0); l.x = f2bf(v0 - bf2f(h.x));
        h.y = f2bf(v1); l.y = f2bf(v1 - bf2f(h.y));
        h.z = f2bf(v2); l.z = f2bf(v2 - bf2f(h.z));
        h.w = f2bf(v3); l.w = f2bf(v3 - bf2f(h.w));
        const size_t o = ((size_t)b * 512 + d0 + dl) * 2048 + i0 + i4 * 4;
        *(ushort4*)(tHi + o) = h;
        *(ushort4*)(tLo + o) = l;
    }
}

// ---------------------------------------------------------------------------
// Scores v3: 256x256 tile, BK=32, 8 waves (2x4), split-3 MFMA.
// 2-barrier overlap schedule per K-step:
//   [issue A0 reads] [Q0: A0xB0] [issue A1 reads] [Q1: A0xB1]
//   lgkm(0)+bar  -> stage(t+2) into buf[t&1]
//   [Q2: A1xB0]  vmcnt(8)+bar -> [issue B(t+1) reads] [Q3: A1xB1]
// B frags held in regs across the K-step boundary; counted vmcnt never 0
// in steady state. LDS layout + swizzle identical to round 1 (0 conflicts).
// ---------------------------------------------------------------------------
__global__ __launch_bounds__(512, 2) void scores_mfma8(
    const unsigned short* __restrict__ Agh, const unsigned short* __restrict__ Agl,
    const unsigned short* __restrict__ Bgh, const unsigned short* __restrict__ Bgl,
    float* __restrict__ attn)
{
    __shared__ __attribute__((aligned(16))) unsigned short S[65536];  // 128 KiB

    const int id = blockIdx.x;
    const int b = id & 7, seq = id >> 3;
    const int ix = seq & 7, oy = seq >> 3;
    const int tid = threadIdx.x;
    const int wave = tid >> 6, lane = tid & 63;
    const int wr = wave >> 2, wc = wave & 3;       // wave tile: rows wr*128, cols wc*64
    const int c16 = lane & 15;
    // swizzled read chunk: q ^ row[2:1]
    const int sq8 = (((lane >> 4) ^ ((c16 >> 1) & 3)) << 3);
    const int aBase = (wr * 128 + c16) * 32 + sq8;
    const int bBase = (wc * 64 + c16) * 32 + sq8;

    // staging: per issue, 512 threads cover 128 rows x 32 shorts (8 KB)
    const int srow = lane >> 2;
    const int kswz = (((lane & 3) ^ ((lane >> 3) & 3)) << 3);   // pre-swizzled source chunk
    const int ldsW = wave * 512;                                 // wave*16 rows * 32 shorts
    const size_t gA = (size_t)(b * 2048 + oy * 256 + wave * 16 + srow) * 512 + kswz;
    const size_t gB = (size_t)(b * 2048 + ix * 256 + wave * 16 + srow) * 512 + kswz;

    auto stageB = [&](int s) {
        unsigned short* D = &S[(s & 1) << 15];
        const int kks = s << 5;
        async16(&D[16384 + ldsW], Bgh + gB + kks);
        async16(&D[20480 + ldsW], Bgh + gB + 65536 + kks);
        async16(&D[24576 + ldsW], Bgl + gB + kks);
        async16(&D[28672 + ldsW], Bgl + gB + 65536 + kks);
    };
    auto stageA = [&](int s) {
        unsigned short* D = &S[(s & 1) << 15];
        const int kks = s << 5;
        async16(&D[0 + ldsW],     Agh + gA + kks);
        async16(&D[4096 + ldsW],  Agh + gA + 65536 + kks);
        async16(&D[8192 + ldsW],  Agl + gA + kks);
        async16(&D[12288 + ldsW], Agl + gA + 65536 + kks);
    };

    f4v acc[8][4];
#pragma unroll
    for (int i = 0; i < 8; ++i)
#pragma unroll
        for (int j = 0; j < 4; ++j) acc[i][j] = (f4v)0.0f;

    // prologue: stage K-steps 0 and 1; wait step 0 (8 newest = step 1 in flight)
    stageB(0); stageA(0);
    stageB(1); stageA(1);
    asm volatile("s_waitcnt vmcnt(8)" ::: "memory");
    phase_barrier();

    // B(0) frags (held in regs across each K-step)
    s8v bh[4], bl[4];
#pragma unroll
    for (int n = 0; n < 4; ++n) {
        bh[n] = *(const s8v*)&S[16384 + bBase + n * 512];
        bl[n] = *(const s8v*)&S[24576 + bBase + n * 512];
    }

    for (int t = 0; t < 16; ++t) {
        const unsigned short* Sb = &S[(t & 1) << 15];
        s8v ah0[4], al0[4], ah1[4], al1[4];

        // issue A0 reads (rows m0..3 of wave tile)
#pragma unroll
        for (int m = 0; m < 4; ++m) {
            ah0[m] = *(const s8v*)&Sb[aBase + m * 512];
            al0[m] = *(const s8v*)&Sb[8192 + aBase + m * 512];
        }
        // Q0: A0 x B0 (n=0,1) — 24 MFMA; compiler inserts lgkm wait for A0/B
        __builtin_amdgcn_s_setprio(1);
#pragma unroll
        for (int m = 0; m < 4; ++m)
#pragma unroll
            for (int n = 0; n < 2; ++n) {
                acc[m][n] = __builtin_amdgcn_mfma_f32_16x16x32_bf16(ah0[m], bh[n], acc[m][n], 0, 0, 0);
                acc[m][n] = __builtin_amdgcn_mfma_f32_16x16x32_bf16(ah0[m], bl[n], acc[m][n], 0, 0, 0);
                acc[m][n] = __builtin_amdgcn_mfma_f32_16x16x32_bf16(al0[m], bh[n], acc[m][n], 0, 0, 0);
            }
        __builtin_amdgcn_s_setprio(0);

        // issue A1 reads (rows m4..7) — overlap with Q1's MFMAs
#pragma unroll
        for (int m = 0; m < 4; ++m) {
            ah1[m] = *(const s8v*)&Sb[aBase + 2048 + m * 512];
            al1[m] = *(const s8v*)&Sb[8192 + aBase + 2048 + m * 512];
        }
        // Q1: A0 x B1 (n=2,3)
        __builtin_amdgcn_s_setprio(1);
#pragma unroll
        for (int m = 0; m < 4; ++m)
#pragma unroll
            for (int n = 2; n < 4; ++n) {
                acc[m][n] = __builtin_amdgcn_mfma_f32_16x16x32_bf16(ah0[m], bh[n], acc[m][n], 0, 0, 0);
                acc[m][n] = __builtin_amdgcn_mfma_f32_16x16x32_bf16(ah0[m], bl[n], acc[m][n], 0, 0, 0);
                acc[m][n] = __builtin_amdgcn_mfma_f32_16x16x32_bf16(al0[m], bh[n], acc[m][n], 0, 0, 0);
            }
        __builtin_amdgcn_s_setprio(0);

        // all reads of buf[t&1] must retire before other waves' DMA overwrites
        asm volatile("s_waitcnt lgkmcnt(0)" ::: "memory");
        __builtin_amdgcn_sched_barrier(0);
        phase_barrier();

        // stage K-step t+2 into buf[t&1] (just fully consumed)
        if (t < 14) { stageB(t + 2); stageA(t + 2); }

        // Q2: A1 x B0 — overlaps stage issue
        __builtin_amdgcn_s_setprio(1);
#pragma unroll
        for (int m = 0; m < 4; ++m)
#pragma unroll
            for (int n = 0; n < 2; ++n) {
                acc[m + 4][n] = __builtin_amdgcn_mfma_f32_16x16x32_bf16(ah1[m], bh[n], acc[m + 4][n], 0, 0, 0);
                acc[m + 4][n] = __builtin_amdgcn_mfma_f32_16x16x32_bf16(ah1[m], bl[n], acc[m + 4][n], 0, 0, 0);
                acc[m + 4][n] = __builtin_amdgcn_mfma_f32_16x16x32_bf16(al1[m], bh[n], acc[m + 4][n], 0, 0, 0);
            }
        __builtin_amdgcn_s_setprio(0);

        // counted wait: K-step t+1's loads landed (t+2's 8 stay in flight)
        if (t < 14) {
            asm volatile("s_waitcnt vmcnt(8)" ::: "memory");
        } else if (t == 14) {
            asm volatile("s_waitcnt vmcnt(0)" ::: "memory");
        }
        phase_barrier();

        // issue B(t+1) reads from the now-ready buffer — overlap with Q3
        s8v nbh[4], nbl[4];
        if (t < 15) {
            const unsigned short* Sn = &S[((t + 1) & 1) << 15];
#pragma unroll
            for (int n = 0; n < 4; ++n) {
                nbh[n] = *(const s8v*)&Sn[16384 + bBase + n * 512];
                nbl[n] = *(const s8v*)&Sn[24576 + bBase + n * 512];
            }
        }
        // Q3: A1 x B1
        __builtin_amdgcn_s_setprio(1);
#pragma unroll
        for (int m = 0; m < 4; ++m)
#pragma unroll
            for (int n = 2; n < 4; ++n) {
                acc[m + 4][n] = __builtin_amdgcn_mfma_f32_16x16x32_bf16(ah1[m], bh[n], acc[m + 4][n], 0, 0, 0);
                acc[m + 4][n] = __builtin_amdgcn_mfma_f32_16x16x32_bf16(ah1[m], bl[n], acc[m + 4][n], 0, 0, 0);
                acc[m + 4][n] = __builtin_amdgcn_mfma_f32_16x16x32_bf16(al1[m], bh[n], acc[m + 4][n], 0, 0, 0);
            }
        __builtin_amdgcn_s_setprio(0);

        if (t < 15) {
#pragma unroll
            for (int n = 0; n < 4; ++n) { bh[n] = nbh[n]; bl[n] = nbl[n]; }
        }
    }

    float* dst = attn + ((size_t)(b * 2048 + oy * 256 + wr * 128)) * 2048 + ix * 256 + wc * 64;
    const int q4 = (lane >> 4) * 4;
#pragma unroll
    for (int mt = 0; mt < 8; ++mt)
#pragma unroll
        for (int nt = 0; nt < 4; ++nt)
#pragma unroll
            for (int r = 0; r < 4; ++r)
                dst[(size_t)(mt * 16 + q4 + r) * 2048 + nt * 16 + c16] = acc[mt][nt][r];
}

// ---------------------------------------------------------------------------
// Softmax: in-place; optionally emits bf16 copy of the final probabilities.
// ---------------------------------------------------------------------------
__global__ __launch_bounds__(256) void softmax_kernel(
    float* __restrict__ attn, unsigned short* __restrict__ attn_bf)
{
    const size_t base = (size_t)blockIdx.x * 2048;
    const int tid = threadIdx.x;
    float4 v0 = *(float4*)(attn + base + tid * 4);
    float4 v1 = *(float4*)(attn + base + 1024 + tid * 4);

    float mx = fmaxf(fmaxf(fmaxf(v0.x, v0.y), fmaxf(v0.z, v0.w)),
                     fmaxf(fmaxf(v1.x, v1.y), fmaxf(v1.z, v1.w)));
#pragma unroll
    for (int off = 32; off > 0; off >>= 1) mx = fmaxf(mx, __shfl_down(mx, off));

    __shared__ float red[4];
    const int wave = tid >> 6, lane = tid & 63;
    if (lane == 0) red[wave] = mx;
    __syncthreads();
    if (tid == 0) red[0] = fmaxf(fmaxf(red[0], red[1]), fmaxf(red[2], red[3]));
    __syncthreads();
    mx = red[0];
    __syncthreads();

    v0.x = expf(v0.x - mx); v0.y = expf(v0.y - mx);
    v0.z = expf(v0.z - mx); v0.w = expf(v0.w - mx);
    v1.x = expf(v1.x - mx); v1.y = expf(v1.y - mx);
    v1.z = expf(v1.z - mx); v1.w = expf(v1.w - mx);

    float s = v0.x + v0.y + v0.z + v0.w + v1.x + v1.y + v1.z + v1.w;
#pragma unroll
    for (int off = 32; off > 0; off >>= 1) s += __shfl_down(s, off);
    if (lane == 0) red[wave] = s;
    __syncthreads();
    if (tid == 0) red[0] = red[0] + red[1] + red[2] + red[3];
    __syncthreads();
    const float inv = 1.0f / red[0];

    v0.x *= inv; v0.y *= inv; v0.z *= inv; v0.w *= inv;
    v1.x *= inv; v1.y *= inv; v1.z *= inv; v1.w *= inv;
    *(float4*)(attn + base + tid * 4) = v0;
    *(float4*)(attn + base + 1024 + tid * 4) = v1;

    if (attn_bf) {
        ushort4 h0, h1;
        h0.x = f2bf(v0.x); h0.y = f2bf(v0.y); h0.z = f2bf(v0.z); h0.w = f2bf(v0.w);
        h1.x = f2bf(v1.x); h1.y = f2bf(v1.y); h1.z = f2bf(v1.z); h1.w = f2bf(v1.w);
        *(ushort4*)(attn_bf + base + tid * 4) = h0;
        *(ushort4*)(attn_bf + base + 1024 + tid * 4) = h1;
    }
}

// ---------------------------------------------------------------------------
// PV tier-1: A = attn_bf (async staged), B = ctxT hi/lo (2 MFMA).
// 1D grid 512: b=id&7, nx inner. Writes mix as bf16 hi/lo.
// ---------------------------------------------------------------------------
__global__ __launch_bounds__(256) void pv_mfma_bf(
    const unsigned short* __restrict__ attn_bf,
    const unsigned short* __restrict__ Bgh, const unsigned short* __restrict__ Bgl,
    unsigned short* __restrict__ mixHi, unsigned short* __restrict__ mixLo)
{
    __shared__ __attribute__((aligned(16))) unsigned short Ab[128 * 32],
                                                           Bh[128 * 32], Bl[128 * 32];
    const int id = blockIdx.x;
    const int b = id & 7, seq = id >> 3;
    const int nx = seq & 3, my = seq >> 2;
    const int tid = threadIdx.x, wave = tid >> 6, lane = tid & 63;
    const int wm = wave >> 1, wn = wave & 1;
    const int c16 = lane & 15, q8 = (lane >> 4) * 8;

    const size_t arow = (size_t)(b * 2048 + my * 128);
    const size_t brow = (size_t)(b * 512 + nx * 128);

    f4v acc[4][4];
#pragma unroll
    for (int i = 0; i < 4; ++i)
#pragma unroll
        for (int j = 0; j < 4; ++j) acc[i][j] = (f4v)0.0f;

    for (int kk = 0; kk < 2048; kk += 32) {
#pragma unroll
        for (int it = 0; it < 2; ++it) {
            const int r0 = it * 64 + wave * 16;
            const int rr = r0 + (lane >> 2);
            const size_t ga = (arow + rr) * 2048 + kk + (lane & 3) * 8;
            const size_t gb = (brow + rr) * 2048 + kk + (lane & 3) * 8;
            async16(&Ab[r0 * 32], attn_bf + ga);
            async16(&Bh[r0 * 32], Bgh + gb);
            async16(&Bl[r0 * 32], Bgl + gb);
        }
        __syncthreads();
        s8v ab[4], bh[4], bl[4];
#pragma unroll
        for (int t = 0; t < 4; ++t) {
            ab[t] = *(const s8v*)&Ab[(wm * 64 + t * 16 + c16) * 32 + q8];
            bh[t] = *(const s8v*)&Bh[(wn * 64 + t * 16 + c16) * 32 + q8];
            bl[t] = *(const s8v*)&Bl[(wn * 64 + t * 16 + c16) * 32 + q8];
        }
#pragma unroll
        for (int mt = 0; mt < 4; ++mt)
#pragma unroll
            for (int nt = 0; nt < 4; ++nt) {
                acc[mt][nt] = __builtin_amdgcn_mfma_f32_16x16x32_bf16(ab[mt], bh[nt], acc[mt][nt], 0, 0, 0);
                acc[mt][nt] = __builtin_amdgcn_mfma_f32_16x16x32_bf16(ab[mt], bl[nt], acc[mt][nt], 0, 0, 0);
            }
        __syncthreads();
    }
    const int q4 = (lane >> 4) * 4;
    const size_t mrow = (size_t)(b * 2048 + my * 128 + wm * 64);
#pragma unroll
    for (int mt = 0; mt < 4; ++mt)
#pragma unroll
        for (int nt = 0; nt < 4; ++nt) {
            const int col = nx * 128 + wn * 64 + nt * 16 + c16;
#pragma unroll
            for (int r = 0; r < 4; ++r) {
                float v = acc[mt][nt][r];
                unsigned short h = f2bf(v);
                unsigned short l = f2bf(v - bf2f(h));
                const size_t o = (mrow + mt * 16 + q4 + r) * 512 + col;
                mixHi[o] = h; mixLo[o] = l;
            }
        }
}

// ---------------------------------------------------------------------------
// PV tier-2 (round-1 structure + swizzle): A = f32 attn converted inline.
// ---------------------------------------------------------------------------
__global__ __launch_bounds__(256) void pv_mfma_cvt(
    const float* __restrict__ attn,
    const unsigned short* __restrict__ Bgh, const unsigned short* __restrict__ Bgl,
    unsigned short* __restrict__ mixHi, unsigned short* __restrict__ mixLo)
{
    __shared__ __attribute__((aligned(16))) unsigned short Ab[128 * 32],
                                                           Bh[128 * 32], Bl[128 * 32];
    const int id = blockIdx.x;
    const int b = id & 7, seq = id >> 3;
    const int nx = seq & 3, my = seq >> 2;
    const int tid = threadIdx.x, wave = tid >> 6, lane = tid & 63;
    const int wm = wave >> 1, wn = wave & 1;
    const int c16 = lane & 15, q8 = (lane >> 4) * 8;

    const float* Abase = attn + ((size_t)b * 2048 + my * 128) * 2048;
    const size_t brow = (size_t)(b * 512 + nx * 128);

    f4v acc[4][4];
#pragma unroll
    for (int i = 0; i < 4; ++i)
#pragma unroll
        for (int j = 0; j < 4; ++j) acc[i][j] = (f4v)0.0f;

    for (int kk = 0; kk < 2048; kk += 32) {
#pragma unroll
        for (int it = 0; it < 4; ++it) {
            const int idx = tid + it * 256;
            const int r = idx >> 3, kc = idx & 7;
            float4 v = *(const float4*)(Abase + (size_t)r * 2048 + kk + kc * 4);
            ushort4 h;
            h.x = f2bf(v.x); h.y = f2bf(v.y); h.z = f2bf(v.z); h.w = f2bf(v.w);
            *(ushort4*)&Ab[r * 32 + kc * 4] = h;
        }
#pragma unroll
        for (int it = 0; it < 2; ++it) {
            const int r0 = it * 64 + wave * 16;
            const size_t gb = (brow + r0 + (lane >> 2)) * 2048 + kk + (lane & 3) * 8;
            async16(&Bh[r0 * 32], Bgh + gb);
            async16(&Bl[r0 * 32], Bgl + gb);
        }
        __syncthreads();
        s8v ab[4], bh[4], bl[4];
#pragma unroll
        for (int t = 0; t < 4; ++t) {
            ab[t] = *(const s8v*)&Ab[(wm * 64 + t * 16 + c16) * 32 + q8];
            bh[t] = *(const s8v*)&Bh[(wn * 64 + t * 16 + c16) * 32 + q8];
            bl[t] = *(const s8v*)&Bl[(wn * 64 + t * 16 + c16) * 32 + q8];
        }
#pragma unroll
        for (int mt = 0; mt < 4; ++mt)
#pragma unroll
            for (int nt = 0; nt < 4; ++nt) {
                acc[mt][nt] = __builtin_amdgcn_mfma_f32_16x16x32_bf16(ab[mt], bh[nt], acc[mt][nt], 0, 0, 0);
                acc[mt][nt] = __builtin_amdgcn_mfma_f32_16x16x32_bf16(ab[mt], bl[nt], acc[mt][nt], 0, 0, 0);
            }
        __syncthreads();
    }
    const int q4 = (lane >> 4) * 4;
    const size_t mrow = (size_t)(b * 2048 + my * 128 + wm * 64);
#pragma unroll
    for (int mt = 0; mt < 4; ++mt)
#pragma unroll
        for (int nt = 0; nt < 4; ++nt) {
            const int col = nx * 128 + wn * 64 + nt * 16 + c16;
#pragma unroll
            for (int r = 0; r < 4; ++r) {
                float v = acc[mt][nt][r];
                unsigned short h = f2bf(v);
                unsigned short l = f2bf(v - bf2f(h));
                const size_t o = (mrow + mt * 16 + q4 + r) * 512 + col;
                mixHi[o] = h; mixLo[o] = l;
            }
        }
}

// ---------------------------------------------------------------------------
// Linear: full split-3, fused bias+tanh. 1D grid 512:
// xcd=id&7 -> my%8, nx inner per-XCD (A tile fetched once, W set L2-resident)
// ---------------------------------------------------------------------------
__global__ __launch_bounds__(256) void linear_mfma(
    const unsigned short* __restrict__ mixHi, const unsigned short* __restrict__ mixLo,
    const unsigned short* __restrict__ outHi, const unsigned short* __restrict__ outLo,
    const unsigned short* __restrict__ Wh, const unsigned short* __restrict__ Wl,
    const float* __restrict__ bias, float* __restrict__ dst)
{
    __shared__ __attribute__((aligned(16))) unsigned short Ah[128 * 32], Al[128 * 32],
                                                           Bh[128 * 32], Bl[128 * 32];
    const int id = blockIdx.x;
    const int xcd = id & 7, seq = id >> 3;
    const int nx = seq & 3;
    const int my = (seq >> 2) * 8 + xcd;
    const int tid = threadIdx.x, wave = tid >> 6, lane = tid & 63;
    const int wm = wave >> 1, wn = wave & 1;
    const int c16 = lane & 15, q8 = (lane >> 4) * 8;

    f4v acc[4][4];
#pragma unroll
    for (int i = 0; i < 4; ++i)
#pragma unroll
        for (int j = 0; j < 4; ++j) acc[i][j] = (f4v)0.0f;

    for (int kk = 0; kk < 1024; kk += 32) {
        const unsigned short* ah_src = (kk < 512) ? mixHi : outHi;
        const unsigned short* al_src = (kk < 512) ? mixLo : outLo;
        const int kc0 = (kk < 512) ? kk : kk - 512;
#pragma unroll
        for (int it = 0; it < 2; ++it) {
            const int r0 = it * 64 + wave * 16;
            const size_t ga = (size_t)(my * 128 + r0 + (lane >> 2)) * 512 + kc0 + (lane & 3) * 8;
            const size_t gb = (size_t)(nx * 128 + r0 + (lane >> 2)) * 1024 + kk + (lane & 3) * 8;
            async16(&Ah[r0 * 32], ah_src + ga);
            async16(&Al[r0 * 32], al_src + ga);
            async16(&Bh[r0 * 32], Wh + gb);
            async16(&Bl[r0 * 32], Wl + gb);
        }
        __syncthreads();
        s8v ah[4], al[4], bh[4], bl[4];
#pragma unroll
        for (int t = 0; t < 4; ++t) {
            ah[t] = *(const s8v*)&Ah[(wm * 64 + t * 16 + c16) * 32 + q8];
            al[t] = *(const s8v*)&Al[(wm * 64 + t * 16 + c16) * 32 + q8];
            bh[t] = *(const s8v*)&Bh[(wn * 64 + t * 16 + c16) * 32 + q8];
            bl[t] = *(const s8v*)&Bl[(wn * 64 + t * 16 + c16) * 32 + q8];
        }
#pragma unroll
        for (int mt = 0; mt < 4; ++mt)
#pragma unroll
            for (int nt = 0; nt < 4; ++nt) {
                acc[mt][nt] = __builtin_amdgcn_mfma_f32_16x16x32_bf16(ah[mt], bh[nt], acc[mt][nt], 0, 0, 0);
                acc[mt][nt] = __builtin_amdgcn_mfma_f32_16x16x32_bf16(ah[mt], bl[nt], acc[mt][nt], 0, 0, 0);
                acc[mt][nt] = __builtin_amdgcn_mfma_f32_16x16x32_bf16(al[mt], bh[nt], acc[mt][nt], 0, 0, 0);
            }
        __syncthreads();
    }
    const int q4 = (lane >> 4) * 4;
#pragma unroll
    for (int mt = 0; mt < 4; ++mt)
#pragma unroll
        for (int nt = 0; nt < 4; ++nt) {
            const int col = nx * 128 + wn * 64 + nt * 16 + c16;
            const float bb = bias[col];
#pragma unroll
            for (int r = 0; r < 4; ++r) {
                const size_t row = (size_t)(my * 128 + wm * 64 + mt * 16 + q4 + r);
                dst[row * 512 + col] = tanhf(acc[mt][nt][r] + bb);
            }
        }
}

// ===========================================================================
// Fallback f32 path
// ===========================================================================
#define BK 32
#define PAD 68

__global__ __launch_bounds__(256) void scores_f32(
    const float* __restrict__ outp, const float* __restrict__ ctx,
    float* __restrict__ attn)
{
    __shared__ float As[BK][PAD];
    __shared__ float Bs[BK][PAD];
    const int b = blockIdx.z, oy = blockIdx.y, ix = blockIdx.x;
    const int tid = threadIdx.x;
    const int tx = tid & 15, ty = tid >> 4;
    const float* Abase = outp + ((size_t)b * 2048 + oy * 64) * 512;
    const float* Bbase = ctx  + ((size_t)b * 2048 + ix * 64) * 512;
    float acc[4][4] = {};
    for (int kk = 0; kk < 512; kk += BK) {
#pragma unroll
        for (int h = 0; h < 2; ++h) {
            const int f = tid + h * 256;
            const int row = f >> 3, k4 = f & 7;
            float4 a = *(const float4*)(Abase + (size_t)row * 512 + kk + k4 * 4);
            float4 c = *(const float4*)(Bbase + (size_t)row * 512 + kk + k4 * 4);
            As[k4 * 4 + 0][row] = a.x; As[k4 * 4 + 1][row] = a.y;
            As[k4 * 4 + 2][row] = a.z; As[k4 * 4 + 3][row] = a.w;
            Bs[k4 * 4 + 0][row] = c.x; Bs[k4 * 4 + 1][row] = c.y;
            Bs[k4 * 4 + 2][row] = c.z; Bs[k4 * 4 + 3][row] = c.w;
        }
        __syncthreads();
#pragma unroll
        for (int k = 0; k < BK; ++k) {
            float4 av = *(const float4*)&As[k][ty * 4];
            float4 bv = *(const float4*)&Bs[k][tx * 4];
            acc[0][0] += av.x * bv.x; acc[0][1] += av.x * bv.y; acc[0][2] += av.x * bv.z; acc[0][3] += av.x * bv.w;
            acc[1][0] += av.y * bv.x; acc[1][1] += av.y * bv.y; acc[1][2] += av.y * bv.z; acc[1][3] += av.y * bv.w;
            acc[2][0] += av.z * bv.x; acc[2][1] += av.z * bv.y; acc[2][2] += av.z * bv.z; acc[2][3] += av.z * bv.w;
            acc[3][0] += av.w * bv.x; acc[3][1] += av.w * bv.y; acc[3][2] += av.w * bv.z; acc[3][3] += av.w * bv.w;
        }
        __syncthreads();
    }
    float* dst = attn + ((size_t)b * 2048 + oy * 64 + ty * 4) * 2048 + ix * 64 + tx * 4;
#pragma unroll
    for (int i = 0; i < 4; ++i)
        *(float4*)(dst + (size_t)i * 2048) = make_float4(acc[i][0], acc[i][1], acc[i][2], acc[i][3]);
}

__global__ __launch_bounds__(256) void pv_f32(
    const float* __restrict__ attn, const float* __restrict__ ctx,
    float* __restrict__ mix)
{
    __shared__ float As[BK][PAD];
    __shared__ float Bs[BK][PAD];
    const int b = blockIdx.z, my = blockIdx.y, nx = blockIdx.x;
    const int tid = threadIdx.x;
    const int tx = tid & 15, ty = tid >> 4;
    const float* Abase = attn + ((size_t)b * 2048 + my * 64) * 2048;
    const float* Bbase = ctx  + ((size_t)b * 2048) * 512 + nx * 64;
    float acc[4][4] = {};
    for (int kk = 0; kk < 2048; kk += BK) {
#pragma unroll
        for (int h = 0; h < 2; ++h) {
            const int f = tid + h * 256;
            const int row = f >> 3, k4 = f & 7;
            float4 a = *(const float4*)(Abase + (size_t)row * 2048 + kk + k4 * 4);
            As[k4 * 4 + 0][row] = a.x; As[k4 * 4 + 1][row] = a.y;
            As[k4 * 4 + 2][row] = a.z; As[k4 * 4 + 3][row] = a.w;
            const int krow = f >> 4, col4 = f & 15;
            float4 c = *(const float4*)(Bbase + (size_t)(kk + krow) * 512 + col4 * 4);
            *(float4*)&Bs[krow][col4 * 4] = c;
        }
        __syncthreads();
#pragma unroll
        for (int k = 0; k < BK; ++k) {
            float4 av = *(const float4*)&As[k][ty * 4];
            float4 bv = *(const float4*)&Bs[k][tx * 4];
            acc[0][0] += av.x * bv.x; acc[0][1] += av.x * bv.y; acc[0][2] += av.x * bv.z; acc[0][3] += av.x * bv.w;
            acc[1][0] += av.y * bv.x; acc[1][1] += av.y * bv.y; acc[1][2] += av.y * bv.z; acc[1][3] += av.y * bv.w;
            acc[2][0] += av.z * bv.x; acc[2][1] += av.z * bv.y; acc[2][2] += av.z * bv.z; acc[2][3] += av.z * bv.w;
            acc[3][0] += av.w * bv.x; acc[3][1] += av.w * bv.y; acc[3][2] += av.w * bv.z; acc[3][3] += av.w * bv.w;
        }
        __syncthreads();
    }
    float* dst = mix + ((size_t)b * 2048 + my * 64 + ty * 4) * 512 + nx * 64 + tx * 4;
#pragma unroll
    for (int i = 0; i < 4; ++i)
        *(float4*)(dst + (size_t)i * 512) = make_float4(acc[i][0], acc[i][1], acc[i][2], acc[i][3]);
}

__global__ __launch_bounds__(256) void linear_f32(
    const float* __restrict__ mix, const float* __restrict__ outp,
    const float* __restrict__ Wm, const float* __restrict__ bias,
    float* __restrict__ dst)
{
    __shared__ float As[BK][PAD];
    __shared__ float Ws[BK][PAD];
    const int my = blockIdx.y, nx = blockIdx.x;
    const int tid = threadIdx.x;
    const int tx = tid & 15, ty = tid >> 4;
    const int m0 = my * 64, n0 = nx * 64;
    float acc[4][4] = {};
    for (int kk = 0; kk < 1024; kk += BK) {
        const float* Abase = (kk < 512) ? (mix + (size_t)m0 * 512 + kk)
                                        : (outp + (size_t)m0 * 512 + (kk - 512));
#pragma unroll
        for (int h = 0; h < 2; ++h) {
            const int f = tid + h * 256;
            const int row = f >> 3, k4 = f & 7;
            float4 a = *(const float4*)(Abase + (size_t)row * 512 + k4 * 4);
            As[k4 * 4 + 0][row] = a.x; As[k4 * 4 + 1][row] = a.y;
            As[k4 * 4 + 2][row] = a.z; As[k4 * 4 + 3][row] = a.w;
            float4 w = *(const float4*)(Wm + (size_t)(n0 + row) * 1024 + kk + k4 * 4);
            Ws[k4 * 4 + 0][row] = w.x; Ws[k4 * 4 + 1][row] = w.y;
            Ws[k4 * 4 + 2][row] = w.z; Ws[k4 * 4 + 3][row] = w.w;
        }
        __syncthreads();
#pragma unroll
        for (int k = 0; k < BK; ++k) {
            float4 av = *(const float4*)&As[k][ty * 4];
            float4 bv = *(const float4*)&Ws[k][tx * 4];
            acc[0][0] += av.x * bv.x; acc[0][1] += av.x * bv.y; acc[0][2] += av.x * bv.z; acc[0][3] += av.x * bv.w;
            acc[1][0] += av.y * bv.x; acc[1][1] += av.y * bv.y; acc[1][2] += av.y * bv.z; acc[1][3] += av.y * bv.w;
            acc[2][0] += av.z * bv.x; acc[2][1] += av.z * bv.y; acc[2][2] += av.z * bv.z; acc[2][3] += av.z * bv.w;
            acc[3][0] += av.w * bv.x; acc[3][1] += av.w * bv.y; acc[3][2] += av.w * bv.z; acc[3][3] += av.w * bv.w;
        }
        __syncthreads();
    }
#pragma unroll
    for (int i = 0; i < 4; ++i) {
        const int n = n0 + tx * 4;
        float4 bv = *(const float4*)(bias + n);
        float4 v;
        v.x = tanhf(acc[i][0] + bv.x); v.y = tanhf(acc[i][1] + bv.y);
        v.z = tanhf(acc[i][2] + bv.z); v.w = tanhf(acc[i][3] + bv.w);
        *(float4*)(dst + (size_t)(m0 + ty * 4 + i) * 512 + n) = v;
    }
}

// ===========================================================================
extern "C" void kernel_launch(void* const* d_in, const int* in_sizes, int n_in,
                              void* d_out, int out_size, void* d_ws, size_t ws_size,
                              hipStream_t stream) {
    const float* outp = (const float*)d_in[0];   // [8,2048,512]
    const float* ctx  = (const float*)d_in[1];   // [8,2048,512]
    const float* Wm   = (const float*)d_in[2];   // [512,1024]
    const float* bias = (const float*)d_in[3];   // [512]

    float* out  = (float*)d_out;
    float* attn = out + (size_t)8 * 2048 * 512;

    const size_t MB = 1ull << 20;
    const size_t NEED1 = 162 * MB;   // tier-1: +64MB attn_bf, mix aliases ctx
    const size_t NEED2 = 130 * MB;   // tier-2: round-1 layout

    if (ws_size >= NEED1) {
        char* w = (char*)d_ws;
        unsigned short* outp_hi = (unsigned short*)(w);              // 16MB
        unsigned short* outp_lo = (unsigned short*)(w + 16 * MB);
        unsigned short* ctx_hi  = (unsigned short*)(w + 32 * MB);
        unsigned short* ctx_lo  = (unsigned short*)(w + 48 * MB);
        unsigned short* ctxT_hi = (unsigned short*)(w + 64 * MB);
        unsigned short* ctxT_lo = (unsigned short*)(w + 80 * MB);
        unsigned short* W_hi    = (unsigned short*)(w + 96 * MB);
        unsigned short* W_lo    = (unsigned short*)(w + 97 * MB);
        unsigned short* attn_bf = (unsigned short*)(w + 98 * MB);    // 64MB
        // mix aliases ctx_hi/ctx_lo (ctx dead after scores)
        unsigned short* mix_hi  = ctx_hi;
        unsigned short* mix_lo  = ctx_lo;

        split_kernel<<<dim3(8192), 256, 0, stream>>>(outp, outp_hi, outp_lo);
        split_kernel<<<dim3(8192), 256, 0, stream>>>(ctx, ctx_hi, ctx_lo);
        split_kernel<<<dim3(512), 256, 0, stream>>>(Wm, W_hi, W_lo);
        transpose_split_kernel<<<dim3(16, 64, 8), 256, 0, stream>>>(ctx, ctxT_hi, ctxT_lo);

        scores_mfma8<<<dim3(512), 512, 0, stream>>>(outp_hi, outp_lo, ctx_hi, ctx_lo, attn);
        softmax_kernel<<<dim3(16384), 256, 0, stream>>>(attn, attn_bf);
        pv_mfma_bf<<<dim3(512), 256, 0, stream>>>(attn_bf, ctxT_hi, ctxT_lo, mix_hi, mix_lo);
        linear_mfma<<<dim3(512), 256, 0, stream>>>(mix_hi, mix_lo, outp_hi, outp_lo,
                                                   W_hi, W_lo, bias, out);
    } else if (ws_size >= NEED2) {
        char* w = (char*)d_ws;
        unsigned short* outp_hi = (unsigned short*)(w);
        unsigned short* outp_lo = (unsigned short*)(w + 16 * MB);
        unsigned short* ctx_hi  = (unsigned short*)(w + 32 * MB);
        unsigned short* ctx_lo  = (unsigned short*)(w + 48 * MB);
        unsigned short* ctxT_hi = (unsigned short*)(w + 64 * MB);
        unsigned short* ctxT_lo = (unsigned short*)(w + 80 * MB);
        unsigned short* W_hi    = (unsigned short*)(w + 96 * MB);
        unsigned short* W_lo    = (unsigned short*)(w + 97 * MB);
        unsigned short* mix_hi  = (unsigned short*)(w + 98 * MB);
        unsigned short* mix_lo  = (unsigned short*)(w + 114 * MB);

        split_kernel<<<dim3(8192), 256, 0, stream>>>(outp, outp_hi, outp_lo);
        split_kernel<<<dim3(8192), 256, 0, stream>>>(ctx, ctx_hi, ctx_lo);
        split_kernel<<<dim3(512), 256, 0, stream>>>(Wm, W_hi, W_lo);
        transpose_split_kernel<<<dim3(16, 64, 8), 256, 0, stream>>>(ctx, ctxT_hi, ctxT_lo);

        scores_mfma8<<<dim3(512), 512, 0, stream>>>(outp_hi, outp_lo, ctx_hi, ctx_lo, attn);
        softmax_kernel<<<dim3(16384), 256, 0, stream>>>(attn, nullptr);
        pv_mfma_cvt<<<dim3(512), 256, 0, stream>>>(attn, ctxT_hi, ctxT_lo, mix_hi, mix_lo);
        linear_mfma<<<dim3(512), 256, 0, stream>>>(mix_hi, mix_lo, outp_hi, outp_lo,
                                                   W_hi, W_lo, bias, out);
    } else {
        float* mix = (float*)d_ws;
        scores_f32<<<dim3(32, 32, 8), 256, 0, stream>>>(outp, ctx, attn);
        softmax_kernel<<<dim3(16384), 256, 0, stream>>>(attn, nullptr);
        pv_f32<<<dim3(8, 32, 8), 256, 0, stream>>>(attn, ctx, mix);
        linear_f32<<<dim3(8, 256), 256, 0, stream>>>(mix, outp, Wm, bias, out);
    }
}

// Round 4
// 497.059 us; speedup vs baseline: 1.0944x; 1.0245x over previous
//
#include <hip/hip_runtime.h>
#include <math.h>

// B=8, T_OUT=2048, T_IN=2048, D=512
// attn = softmax(outp @ ctx^T); mix = attn @ ctx; out = tanh([mix,outp] @ W^T + b)
// d_out = out (8.4M f32) ++ attn (33.6M f32)
//
// bf16 hi/lo split-MFMA emulation of f32 GEMMs (no fp32 MFMA on CDNA4).
// Round 4: resubmit of round 3 (infra container failure, no counters).
// pv ported to the scores-v3 overlap template: BM=256 BN=128 BK=64,
// 8 waves, 128KiB LDS dbuf, swizzled [r][32] k-slice subtiles (0 conflicts),
// counted vmcnt(8), mid-step lgkm(0)+barrier, stage-2-ahead. scores unchanged.

typedef short s8v __attribute__((ext_vector_type(8)));    // 8 bf16 (4 VGPR)
typedef float f4v __attribute__((ext_vector_type(4)));    // MFMA acc

__device__ __forceinline__ unsigned short f2bf(float f) {
    unsigned int u = __float_as_uint(f);
    u += 0x7fff + ((u >> 16) & 1);           // RNE
    return (unsigned short)(u >> 16);
}
__device__ __forceinline__ float bf2f(unsigned short h) {
    return __uint_as_float(((unsigned int)h) << 16);
}

__device__ __forceinline__ void async16(void* lds, const void* g) {
    __builtin_amdgcn_global_load_lds(
        (const __attribute__((address_space(1))) unsigned int*)g,
        (__attribute__((address_space(3))) unsigned int*)lds, 16, 0, 0);
}

__device__ __forceinline__ void phase_barrier() {
    asm volatile("" ::: "memory");
    __builtin_amdgcn_s_barrier();
    asm volatile("" ::: "memory");
}

// ---------------------------------------------------------------------------
// Prep: elementwise f32 -> bf16 hi/lo split
// ---------------------------------------------------------------------------
__global__ __launch_bounds__(256) void split_kernel(
    const float* __restrict__ src, unsigned short* __restrict__ hi,
    unsigned short* __restrict__ lo)
{
    const size_t i = ((size_t)blockIdx.x * 256 + threadIdx.x) * 4;
    float4 v = *(const float4*)(src + i);
    ushort4 h, l;
    h.x = f2bf(v.x); l.x = f2bf(v.x - bf2f(h.x));
    h.y = f2bf(v.y); l.y = f2bf(v.y - bf2f(h.y));
    h.z = f2bf(v.z); l.z = f2bf(v.z - bf2f(h.z));
    h.w = f2bf(v.w); l.w = f2bf(v.w - bf2f(h.w));
    *(ushort4*)(hi + i) = h;
    *(ushort4*)(lo + i) = l;
}

// ---------------------------------------------------------------------------
// Prep: ctx[b][i][d] f32 -> ctxT_hi/lo[b][d][i] bf16
// ---------------------------------------------------------------------------
__global__ __launch_bounds__(256) void transpose_split_kernel(
    const float* __restrict__ ctx, unsigned short* __restrict__ tHi,
    unsigned short* __restrict__ tLo)
{
    __shared__ float tile[32][33];
    const int b = blockIdx.z, i0 = blockIdx.y * 32, d0 = blockIdx.x * 32;
    const int t = threadIdx.x;
    {
        const int il = t >> 3, d4 = t & 7;
        float4 v = *(const float4*)(ctx + ((size_t)b * 2048 + i0 + il) * 512 + d0 + d4 * 4);
        tile[il][d4 * 4 + 0] = v.x; tile[il][d4 * 4 + 1] = v.y;
        tile[il][d4 * 4 + 2] = v.z; tile[il][d4 * 4 + 3] = v.w;
    }
    __syncthreads();
    {
        const int dl = t >> 3, i4 = t & 7;
        ushort4 h, l;
        float v0 = tile[i4 * 4 + 0][dl], v1 = tile[i4 * 4 + 1][dl];
        float v2 = tile[i4 * 4 + 2][dl], v3 = tile[i4 * 4 + 3][dl];
        h.x = f2bf(v0); l.x = f2bf(v0 - bf2f(h.x));
        h.y = f2bf(v1); l.y = f2bf(v1 - bf2f(h.y));
        h.z = f2bf(v2); l.z = f2bf(v2 - bf2f(h.z));
        h.w = f2bf(v3); l.w = f2bf(v3 - bf2f(h.w));
        const size_t o = ((size_t)b * 512 + d0 + dl) * 2048 + i0 + i4 * 4;
        *(ushort4*)(tHi + o) = h;
        *(ushort4*)(tLo + o) = l;
    }
}

// ---------------------------------------------------------------------------
// Scores v3 (round-2, kept): 256x256 tile, BK=32, 8 waves, split-3 MFMA,
// 2-barrier overlap schedule, counted vmcnt(8), swizzled LDS (0 conflicts).
// ---------------------------------------------------------------------------
__global__ __launch_bounds__(512, 2) void scores_mfma8(
    const unsigned short* __restrict__ Agh, const unsigned short* __restrict__ Agl,
    const unsigned short* __restrict__ Bgh, const unsigned short* __restrict__ Bgl,
    float* __restrict__ attn)
{
    __shared__ __attribute__((aligned(16))) unsigned short S[65536];  // 128 KiB

    const int id = blockIdx.x;
    const int b = id & 7, seq = id >> 3;
    const int ix = seq & 7, oy = seq >> 3;
    const int tid = threadIdx.x;
    const int wave = tid >> 6, lane = tid & 63;
    const int wr = wave >> 2, wc = wave & 3;       // wave tile: rows wr*128, cols wc*64
    const int c16 = lane & 15;
    // swizzled read chunk: q ^ row[2:1]
    const int sq8 = (((lane >> 4) ^ ((c16 >> 1) & 3)) << 3);
    const int aBase = (wr * 128 + c16) * 32 + sq8;
    const int bBase = (wc * 64 + c16) * 32 + sq8;

    // staging: per issue, 512 threads cover 128 rows x 32 shorts (8 KB)
    const int srow = lane >> 2;
    const int kswz = (((lane & 3) ^ ((lane >> 3) & 3)) << 3);   // pre-swizzled source chunk
    const int ldsW = wave * 512;                                 // wave*16 rows * 32 shorts
    const size_t gA = (size_t)(b * 2048 + oy * 256 + wave * 16 + srow) * 512 + kswz;
    const size_t gB = (size_t)(b * 2048 + ix * 256 + wave * 16 + srow) * 512 + kswz;

    auto stageB = [&](int s) {
        unsigned short* D = &S[(s & 1) << 15];
        const int kks = s << 5;
        async16(&D[16384 + ldsW], Bgh + gB + kks);
        async16(&D[20480 + ldsW], Bgh + gB + 65536 + kks);
        async16(&D[24576 + ldsW], Bgl + gB + kks);
        async16(&D[28672 + ldsW], Bgl + gB + 65536 + kks);
    };
    auto stageA = [&](int s) {
        unsigned short* D = &S[(s & 1) << 15];
        const int kks = s << 5;
        async16(&D[0 + ldsW],     Agh + gA + kks);
        async16(&D[4096 + ldsW],  Agh + gA + 65536 + kks);
        async16(&D[8192 + ldsW],  Agl + gA + kks);
        async16(&D[12288 + ldsW], Agl + gA + 65536 + kks);
    };

    f4v acc[8][4];
#pragma unroll
    for (int i = 0; i < 8; ++i)
#pragma unroll
        for (int j = 0; j < 4; ++j) acc[i][j] = (f4v)0.0f;

    // prologue: stage K-steps 0 and 1; wait step 0 (8 newest = step 1 in flight)
    stageB(0); stageA(0);
    stageB(1); stageA(1);
    asm volatile("s_waitcnt vmcnt(8)" ::: "memory");
    phase_barrier();

    // B(0) frags (held in regs across each K-step)
    s8v bh[4], bl[4];
#pragma unroll
    for (int n = 0; n < 4; ++n) {
        bh[n] = *(const s8v*)&S[16384 + bBase + n * 512];
        bl[n] = *(const s8v*)&S[24576 + bBase + n * 512];
    }

    for (int t = 0; t < 16; ++t) {
        const unsigned short* Sb = &S[(t & 1) << 15];
        s8v ah0[4], al0[4], ah1[4], al1[4];

        // issue A0 reads (rows m0..3 of wave tile)
#pragma unroll
        for (int m = 0; m < 4; ++m) {
            ah0[m] = *(const s8v*)&Sb[aBase + m * 512];
            al0[m] = *(const s8v*)&Sb[8192 + aBase + m * 512];
        }
        // Q0: A0 x B0 (n=0,1)
        __builtin_amdgcn_s_setprio(1);
#pragma unroll
        for (int m = 0; m < 4; ++m)
#pragma unroll
            for (int n = 0; n < 2; ++n) {
                acc[m][n] = __builtin_amdgcn_mfma_f32_16x16x32_bf16(ah0[m], bh[n], acc[m][n], 0, 0, 0);
                acc[m][n] = __builtin_amdgcn_mfma_f32_16x16x32_bf16(ah0[m], bl[n], acc[m][n], 0, 0, 0);
                acc[m][n] = __builtin_amdgcn_mfma_f32_16x16x32_bf16(al0[m], bh[n], acc[m][n], 0, 0, 0);
            }
        __builtin_amdgcn_s_setprio(0);

        // issue A1 reads (rows m4..7) — overlap with Q1's MFMAs
#pragma unroll
        for (int m = 0; m < 4; ++m) {
            ah1[m] = *(const s8v*)&Sb[aBase + 2048 + m * 512];
            al1[m] = *(const s8v*)&Sb[8192 + aBase + 2048 + m * 512];
        }
        // Q1: A0 x B1 (n=2,3)
        __builtin_amdgcn_s_setprio(1);
#pragma unroll
        for (int m = 0; m < 4; ++m)
#pragma unroll
            for (int n = 2; n < 4; ++n) {
                acc[m][n] = __builtin_amdgcn_mfma_f32_16x16x32_bf16(ah0[m], bh[n], acc[m][n], 0, 0, 0);
                acc[m][n] = __builtin_amdgcn_mfma_f32_16x16x32_bf16(ah0[m], bl[n], acc[m][n], 0, 0, 0);
                acc[m][n] = __builtin_amdgcn_mfma_f32_16x16x32_bf16(al0[m], bh[n], acc[m][n], 0, 0, 0);
            }
        __builtin_amdgcn_s_setprio(0);

        // all reads of buf[t&1] must retire before other waves' DMA overwrites
        asm volatile("s_waitcnt lgkmcnt(0)" ::: "memory");
        __builtin_amdgcn_sched_barrier(0);
        phase_barrier();

        // stage K-step t+2 into buf[t&1] (just fully consumed)
        if (t < 14) { stageB(t + 2); stageA(t + 2); }

        // Q2: A1 x B0 — overlaps stage issue
        __builtin_amdgcn_s_setprio(1);
#pragma unroll
        for (int m = 0; m < 4; ++m)
#pragma unroll
            for (int n = 0; n < 2; ++n) {
                acc[m + 4][n] = __builtin_amdgcn_mfma_f32_16x16x32_bf16(ah1[m], bh[n], acc[m + 4][n], 0, 0, 0);
                acc[m + 4][n] = __builtin_amdgcn_mfma_f32_16x16x32_bf16(ah1[m], bl[n], acc[m + 4][n], 0, 0, 0);
                acc[m + 4][n] = __builtin_amdgcn_mfma_f32_16x16x32_bf16(al1[m], bh[n], acc[m + 4][n], 0, 0, 0);
            }
        __builtin_amdgcn_s_setprio(0);

        // counted wait: K-step t+1's loads landed (t+2's 8 stay in flight)
        if (t < 14) {
            asm volatile("s_waitcnt vmcnt(8)" ::: "memory");
        } else if (t == 14) {
            asm volatile("s_waitcnt vmcnt(0)" ::: "memory");
        }
        phase_barrier();

        // issue B(t+1) reads from the now-ready buffer — overlap with Q3
        s8v nbh[4], nbl[4];
        if (t < 15) {
            const unsigned short* Sn = &S[((t + 1) & 1) << 15];
#pragma unroll
            for (int n = 0; n < 4; ++n) {
                nbh[n] = *(const s8v*)&Sn[16384 + bBase + n * 512];
                nbl[n] = *(const s8v*)&Sn[24576 + bBase + n * 512];
            }
        }
        // Q3: A1 x B1
        __builtin_amdgcn_s_setprio(1);
#pragma unroll
        for (int m = 0; m < 4; ++m)
#pragma unroll
            for (int n = 2; n < 4; ++n) {
                acc[m + 4][n] = __builtin_amdgcn_mfma_f32_16x16x32_bf16(ah1[m], bh[n], acc[m + 4][n], 0, 0, 0);
                acc[m + 4][n] = __builtin_amdgcn_mfma_f32_16x16x32_bf16(ah1[m], bl[n], acc[m + 4][n], 0, 0, 0);
                acc[m + 4][n] = __builtin_amdgcn_mfma_f32_16x16x32_bf16(al1[m], bh[n], acc[m + 4][n], 0, 0, 0);
            }
        __builtin_amdgcn_s_setprio(0);

        if (t < 15) {
#pragma unroll
            for (int n = 0; n < 4; ++n) { bh[n] = nbh[n]; bl[n] = nbl[n]; }
        }
    }

    float* dst = attn + ((size_t)(b * 2048 + oy * 256 + wr * 128)) * 2048 + ix * 256 + wc * 64;
    const int q4 = (lane >> 4) * 4;
#pragma unroll
    for (int mt = 0; mt < 8; ++mt)
#pragma unroll
        for (int nt = 0; nt < 4; ++nt)
#pragma unroll
            for (int r = 0; r < 4; ++r)
                dst[(size_t)(mt * 16 + q4 + r) * 2048 + nt * 16 + c16] = acc[mt][nt][r];
}

// ---------------------------------------------------------------------------
// Softmax: in-place; optionally emits bf16 copy of the final probabilities.
// ---------------------------------------------------------------------------
__global__ __launch_bounds__(256) void softmax_kernel(
    float* __restrict__ attn, unsigned short* __restrict__ attn_bf)
{
    const size_t base = (size_t)blockIdx.x * 2048;
    const int tid = threadIdx.x;
    float4 v0 = *(float4*)(attn + base + tid * 4);
    float4 v1 = *(float4*)(attn + base + 1024 + tid * 4);

    float mx = fmaxf(fmaxf(fmaxf(v0.x, v0.y), fmaxf(v0.z, v0.w)),
                     fmaxf(fmaxf(v1.x, v1.y), fmaxf(v1.z, v1.w)));
#pragma unroll
    for (int off = 32; off > 0; off >>= 1) mx = fmaxf(mx, __shfl_down(mx, off));

    __shared__ float red[4];
    const int wave = tid >> 6, lane = tid & 63;
    if (lane == 0) red[wave] = mx;
    __syncthreads();
    if (tid == 0) red[0] = fmaxf(fmaxf(red[0], red[1]), fmaxf(red[2], red[3]));
    __syncthreads();
    mx = red[0];
    __syncthreads();

    v0.x = expf(v0.x - mx); v0.y = expf(v0.y - mx);
    v0.z = expf(v0.z - mx); v0.w = expf(v0.w - mx);
    v1.x = expf(v1.x - mx); v1.y = expf(v1.y - mx);
    v1.z = expf(v1.z - mx); v1.w = expf(v1.w - mx);

    float s = v0.x + v0.y + v0.z + v0.w + v1.x + v1.y + v1.z + v1.w;
#pragma unroll
    for (int off = 32; off > 0; off >>= 1) s += __shfl_down(s, off);
    if (lane == 0) red[wave] = s;
    __syncthreads();
    if (tid == 0) red[0] = red[0] + red[1] + red[2] + red[3];
    __syncthreads();
    const float inv = 1.0f / red[0];

    v0.x *= inv; v0.y *= inv; v0.z *= inv; v0.w *= inv;
    v1.x *= inv; v1.y *= inv; v1.z *= inv; v1.w *= inv;
    *(float4*)(attn + base + tid * 4) = v0;
    *(float4*)(attn + base + 1024 + tid * 4) = v1;

    if (attn_bf) {
        ushort4 h0, h1;
        h0.x = f2bf(v0.x); h0.y = f2bf(v0.y); h0.z = f2bf(v0.z); h0.w = f2bf(v0.w);
        h1.x = f2bf(v1.x); h1.y = f2bf(v1.y); h1.z = f2bf(v1.z); h1.w = f2bf(v1.w);
        *(ushort4*)(attn_bf + base + tid * 4) = h0;
        *(ushort4*)(attn_bf + base + 1024 + tid * 4) = h1;
    }
}

// ---------------------------------------------------------------------------
// PV v2: BM=256, BN=128, BK=64 (2 k-slices of 32), 8 waves (2x4),
// A = attn_bf (bf16 single), B = ctxT hi/lo (2-MFMA).
// LDS per buffer (shorts): A [2][256][32] @0, Bh [2][128][32] @16384,
// Bl [2][128][32] @24576; per-slice subtiles use the verified chunk-swizzle.
// Schedule: slice0 {A0 reads, Q0, A1 reads, Q1}, slice1 {A0' + B' reads, Q2,
// A1' reads}, lgkm(0)+bar, stage(t+2), Q3, vmcnt(8)+bar. Grid 256.
// ---------------------------------------------------------------------------
__global__ __launch_bounds__(512, 2) void pv_mfma8(
    const unsigned short* __restrict__ attn_bf,
    const unsigned short* __restrict__ Bgh, const unsigned short* __restrict__ Bgl,
    unsigned short* __restrict__ mixHi, unsigned short* __restrict__ mixLo)
{
    __shared__ __attribute__((aligned(16))) unsigned short S[65536];  // 128 KiB

    const int id = blockIdx.x;
    const int b = id & 7, seq = id >> 3;
    const int nx = seq & 3, my = seq >> 2;         // my 0..7, nx 0..3
    const int tid = threadIdx.x;
    const int wave = tid >> 6, lane = tid & 63;
    const int wr = wave >> 2, wc = wave & 3;       // rows wr*128, cols wc*32
    const int c16 = lane & 15;
    const int sq8 = (((lane >> 4) ^ ((c16 >> 1) & 3)) << 3);
    const int aBase = (wr * 128 + c16) * 32 + sq8;  // within A slice tile [256][32]
    const int bBase = (wc * 32 + c16) * 32 + sq8;   // within B slice tile [128][32]

    const int srow = lane >> 2;
    const int kswz = (((lane & 3) ^ ((lane >> 3) & 3)) << 3);
    const int ldsW = wave * 512;                    // wave*16 rows * 32 shorts

    const size_t gA = (size_t)(b * 2048 + my * 256 + wave * 16 + srow) * 2048 + kswz;
    const size_t gB = (size_t)(b * 512 + nx * 128 + wave * 16 + srow) * 2048 + kswz;

    auto stage = [&](int t) {
        unsigned short* D = &S[(t & 1) << 15];
        const int kk = t << 6;
        // A slices: s*8192, halves: h*4096
        async16(&D[0 + ldsW],            attn_bf + gA + kk);                    // s0 h0
        async16(&D[4096 + ldsW],         attn_bf + gA + (size_t)128 * 2048 + kk);       // s0 h1
        async16(&D[8192 + ldsW],         attn_bf + gA + kk + 32);               // s1 h0
        async16(&D[12288 + ldsW],        attn_bf + gA + (size_t)128 * 2048 + kk + 32);  // s1 h1
        // B: Bh slices @16384 + s*4096, Bl @24576 + s*4096
        async16(&D[16384 + ldsW],        Bgh + gB + kk);
        async16(&D[16384 + 4096 + ldsW], Bgh + gB + kk + 32);
        async16(&D[24576 + ldsW],        Bgl + gB + kk);
        async16(&D[24576 + 4096 + ldsW], Bgl + gB + kk + 32);
    };

    f4v acc[8][2];
#pragma unroll
    for (int i = 0; i < 8; ++i)
#pragma unroll
        for (int j = 0; j < 2; ++j) acc[i][j] = (f4v)0.0f;

    // prologue: stage steps 0,1; wait step 0 (step-1's 8 stay in flight)
    stage(0); stage(1);
    asm volatile("s_waitcnt vmcnt(8)" ::: "memory");
    phase_barrier();

    for (int t = 0; t < 32; ++t) {
        const unsigned short* Sb = &S[(t & 1) << 15];
        s8v a0[4], a1[4], bhf[2], blf[2];

        // ---- slice 0 ----
#pragma unroll
        for (int m = 0; m < 4; ++m) a0[m] = *(const s8v*)&Sb[aBase + m * 512];
#pragma unroll
        for (int n = 0; n < 2; ++n) {
            bhf[n] = *(const s8v*)&Sb[16384 + bBase + n * 512];
            blf[n] = *(const s8v*)&Sb[24576 + bBase + n * 512];
        }
        // Q0: slice0, m0..3
        __builtin_amdgcn_s_setprio(1);
#pragma unroll
        for (int m = 0; m < 4; ++m)
#pragma unroll
            for (int n = 0; n < 2; ++n) {
                acc[m][n] = __builtin_amdgcn_mfma_f32_16x16x32_bf16(a0[m], bhf[n], acc[m][n], 0, 0, 0);
                acc[m][n] = __builtin_amdgcn_mfma_f32_16x16x32_bf16(a0[m], blf[n], acc[m][n], 0, 0, 0);
            }
        __builtin_amdgcn_s_setprio(0);
        // A1 slice0 (rows m4..7)
#pragma unroll
        for (int m = 0; m < 4; ++m) a1[m] = *(const s8v*)&Sb[aBase + 2048 + m * 512];
        // Q1: slice0, m4..7
        __builtin_amdgcn_s_setprio(1);
#pragma unroll
        for (int m = 0; m < 4; ++m)
#pragma unroll
            for (int n = 0; n < 2; ++n) {
                acc[m + 4][n] = __builtin_amdgcn_mfma_f32_16x16x32_bf16(a1[m], bhf[n], acc[m + 4][n], 0, 0, 0);
                acc[m + 4][n] = __builtin_amdgcn_mfma_f32_16x16x32_bf16(a1[m], blf[n], acc[m + 4][n], 0, 0, 0);
            }
        __builtin_amdgcn_s_setprio(0);

        // ---- slice 1 ----
#pragma unroll
        for (int m = 0; m < 4; ++m) a0[m] = *(const s8v*)&Sb[8192 + aBase + m * 512];
#pragma unroll
        for (int n = 0; n < 2; ++n) {
            bhf[n] = *(const s8v*)&Sb[16384 + 4096 + bBase + n * 512];
            blf[n] = *(const s8v*)&Sb[24576 + 4096 + bBase + n * 512];
        }
        // Q2: slice1, m0..3
        __builtin_amdgcn_s_setprio(1);
#pragma unroll
        for (int m = 0; m < 4; ++m)
#pragma unroll
            for (int n = 0; n < 2; ++n) {
                acc[m][n] = __builtin_amdgcn_mfma_f32_16x16x32_bf16(a0[m], bhf[n], acc[m][n], 0, 0, 0);
                acc[m][n] = __builtin_amdgcn_mfma_f32_16x16x32_bf16(a0[m], blf[n], acc[m][n], 0, 0, 0);
            }
        __builtin_amdgcn_s_setprio(0);
        // A1 slice1
#pragma unroll
        for (int m = 0; m < 4; ++m) a1[m] = *(const s8v*)&Sb[8192 + aBase + 2048 + m * 512];

        // all reads of buf[t&1] retired before DMA overwrite
        asm volatile("s_waitcnt lgkmcnt(0)" ::: "memory");
        __builtin_amdgcn_sched_barrier(0);
        phase_barrier();

        if (t < 30) stage(t + 2);

        // Q3: slice1, m4..7 — overlaps stage issue
        __builtin_amdgcn_s_setprio(1);
#pragma unroll
        for (int m = 0; m < 4; ++m)
#pragma unroll
            for (int n = 0; n < 2; ++n) {
                acc[m + 4][n] = __builtin_amdgcn_mfma_f32_16x16x32_bf16(a1[m], bhf[n], acc[m + 4][n], 0, 0, 0);
                acc[m + 4][n] = __builtin_amdgcn_mfma_f32_16x16x32_bf16(a1[m], blf[n], acc[m + 4][n], 0, 0, 0);
            }
        __builtin_amdgcn_s_setprio(0);

        if (t < 30) {
            asm volatile("s_waitcnt vmcnt(8)" ::: "memory");
        } else if (t == 30) {
            asm volatile("s_waitcnt vmcnt(0)" ::: "memory");
        }
        phase_barrier();
    }

    const int q4 = (lane >> 4) * 4;
    const size_t mrow = (size_t)(b * 2048 + my * 256 + wr * 128);
#pragma unroll
    for (int mt = 0; mt < 8; ++mt)
#pragma unroll
        for (int nt = 0; nt < 2; ++nt) {
            const int col = nx * 128 + wc * 32 + nt * 16 + c16;
#pragma unroll
            for (int r = 0; r < 4; ++r) {
                float v = acc[mt][nt][r];
                unsigned short h = f2bf(v);
                unsigned short l = f2bf(v - bf2f(h));
                const size_t o = (mrow + mt * 16 + q4 + r) * 512 + col;
                mixHi[o] = h; mixLo[o] = l;
            }
        }
}

// ---------------------------------------------------------------------------
// PV tier-2 (round-1 structure + swizzle): A = f32 attn converted inline.
// ---------------------------------------------------------------------------
__global__ __launch_bounds__(256) void pv_mfma_cvt(
    const float* __restrict__ attn,
    const unsigned short* __restrict__ Bgh, const unsigned short* __restrict__ Bgl,
    unsigned short* __restrict__ mixHi, unsigned short* __restrict__ mixLo)
{
    __shared__ __attribute__((aligned(16))) unsigned short Ab[128 * 32],
                                                           Bh[128 * 32], Bl[128 * 32];
    const int id = blockIdx.x;
    const int b = id & 7, seq = id >> 3;
    const int nx = seq & 3, my = seq >> 2;
    const int tid = threadIdx.x, wave = tid >> 6, lane = tid & 63;
    const int wm = wave >> 1, wn = wave & 1;
    const int c16 = lane & 15, q8 = (lane >> 4) * 8;

    const float* Abase = attn + ((size_t)b * 2048 + my * 128) * 2048;
    const size_t brow = (size_t)(b * 512 + nx * 128);

    f4v acc[4][4];
#pragma unroll
    for (int i = 0; i < 4; ++i)
#pragma unroll
        for (int j = 0; j < 4; ++j) acc[i][j] = (f4v)0.0f;

    for (int kk = 0; kk < 2048; kk += 32) {
#pragma unroll
        for (int it = 0; it < 4; ++it) {
            const int idx = tid + it * 256;
            const int r = idx >> 3, kc = idx & 7;
            float4 v = *(const float4*)(Abase + (size_t)r * 2048 + kk + kc * 4);
            ushort4 h;
            h.x = f2bf(v.x); h.y = f2bf(v.y); h.z = f2bf(v.z); h.w = f2bf(v.w);
            *(ushort4*)&Ab[r * 32 + kc * 4] = h;
        }
#pragma unroll
        for (int it = 0; it < 2; ++it) {
            const int r0 = it * 64 + wave * 16;
            const size_t gb = (brow + r0 + (lane >> 2)) * 2048 + kk + (lane & 3) * 8;
            async16(&Bh[r0 * 32], Bgh + gb);
            async16(&Bl[r0 * 32], Bgl + gb);
        }
        __syncthreads();
        s8v ab[4], bh[4], bl[4];
#pragma unroll
        for (int t = 0; t < 4; ++t) {
            ab[t] = *(const s8v*)&Ab[(wm * 64 + t * 16 + c16) * 32 + q8];
            bh[t] = *(const s8v*)&Bh[(wn * 64 + t * 16 + c16) * 32 + q8];
            bl[t] = *(const s8v*)&Bl[(wn * 64 + t * 16 + c16) * 32 + q8];
        }
#pragma unroll
        for (int mt = 0; mt < 4; ++mt)
#pragma unroll
            for (int nt = 0; nt < 4; ++nt) {
                acc[mt][nt] = __builtin_amdgcn_mfma_f32_16x16x32_bf16(ab[mt], bh[nt], acc[mt][nt], 0, 0, 0);
                acc[mt][nt] = __builtin_amdgcn_mfma_f32_16x16x32_bf16(ab[mt], bl[nt], acc[mt][nt], 0, 0, 0);
            }
        __syncthreads();
    }
    const int q4 = (lane >> 4) * 4;
    const size_t mrow = (size_t)(b * 2048 + my * 128 + wm * 64);
#pragma unroll
    for (int mt = 0; mt < 4; ++mt)
#pragma unroll
        for (int nt = 0; nt < 4; ++nt) {
            const int col = nx * 128 + wn * 64 + nt * 16 + c16;
#pragma unroll
            for (int r = 0; r < 4; ++r) {
                float v = acc[mt][nt][r];
                unsigned short h = f2bf(v);
                unsigned short l = f2bf(v - bf2f(h));
                const size_t o = (mrow + mt * 16 + q4 + r) * 512 + col;
                mixHi[o] = h; mixLo[o] = l;
            }
        }
}

// ---------------------------------------------------------------------------
// Linear: full split-3, fused bias+tanh. 1D grid 512:
// xcd=id&7 -> my%8, nx inner per-XCD (A tile fetched once, W set L2-resident)
// ---------------------------------------------------------------------------
__global__ __launch_bounds__(256) void linear_mfma(
    const unsigned short* __restrict__ mixHi, const unsigned short* __restrict__ mixLo,
    const unsigned short* __restrict__ outHi, const unsigned short* __restrict__ outLo,
    const unsigned short* __restrict__ Wh, const unsigned short* __restrict__ Wl,
    const float* __restrict__ bias, float* __restrict__ dst)
{
    __shared__ __attribute__((aligned(16))) unsigned short Ah[128 * 32], Al[128 * 32],
                                                           Bh[128 * 32], Bl[128 * 32];
    const int id = blockIdx.x;
    const int xcd = id & 7, seq = id >> 3;
    const int nx = seq & 3;
    const int my = (seq >> 2) * 8 + xcd;
    const int tid = threadIdx.x, wave = tid >> 6, lane = tid & 63;
    const int wm = wave >> 1, wn = wave & 1;
    const int c16 = lane & 15, q8 = (lane >> 4) * 8;

    f4v acc[4][4];
#pragma unroll
    for (int i = 0; i < 4; ++i)
#pragma unroll
        for (int j = 0; j < 4; ++j) acc[i][j] = (f4v)0.0f;

    for (int kk = 0; kk < 1024; kk += 32) {
        const unsigned short* ah_src = (kk < 512) ? mixHi : outHi;
        const unsigned short* al_src = (kk < 512) ? mixLo : outLo;
        const int kc0 = (kk < 512) ? kk : kk - 512;
#pragma unroll
        for (int it = 0; it < 2; ++it) {
            const int r0 = it * 64 + wave * 16;
            const size_t ga = (size_t)(my * 128 + r0 + (lane >> 2)) * 512 + kc0 + (lane & 3) * 8;
            const size_t gb = (size_t)(nx * 128 + r0 + (lane >> 2)) * 1024 + kk + (lane & 3) * 8;
            async16(&Ah[r0 * 32], ah_src + ga);
            async16(&Al[r0 * 32], al_src + ga);
            async16(&Bh[r0 * 32], Wh + gb);
            async16(&Bl[r0 * 32], Wl + gb);
        }
        __syncthreads();
        s8v ah[4], al[4], bh[4], bl[4];
#pragma unroll
        for (int t = 0; t < 4; ++t) {
            ah[t] = *(const s8v*)&Ah[(wm * 64 + t * 16 + c16) * 32 + q8];
            al[t] = *(const s8v*)&Al[(wm * 64 + t * 16 + c16) * 32 + q8];
            bh[t] = *(const s8v*)&Bh[(wn * 64 + t * 16 + c16) * 32 + q8];
            bl[t] = *(const s8v*)&Bl[(wn * 64 + t * 16 + c16) * 32 + q8];
        }
#pragma unroll
        for (int mt = 0; mt < 4; ++mt)
#pragma unroll
            for (int nt = 0; nt < 4; ++nt) {
                acc[mt][nt] = __builtin_amdgcn_mfma_f32_16x16x32_bf16(ah[mt], bh[nt], acc[mt][nt], 0, 0, 0);
                acc[mt][nt] = __builtin_amdgcn_mfma_f32_16x16x32_bf16(ah[mt], bl[nt], acc[mt][nt], 0, 0, 0);
                acc[mt][nt] = __builtin_amdgcn_mfma_f32_16x16x32_bf16(al[mt], bh[nt], acc[mt][nt], 0, 0, 0);
            }
        __syncthreads();
    }
    const int q4 = (lane >> 4) * 4;
#pragma unroll
    for (int mt = 0; mt < 4; ++mt)
#pragma unroll
        for (int nt = 0; nt < 4; ++nt) {
            const int col = nx * 128 + wn * 64 + nt * 16 + c16;
            const float bb = bias[col];
#pragma unroll
            for (int r = 0; r < 4; ++r) {
                const size_t row = (size_t)(my * 128 + wm * 64 + mt * 16 + q4 + r);
                dst[row * 512 + col] = tanhf(acc[mt][nt][r] + bb);
            }
        }
}

// ===========================================================================
// Fallback f32 path
// ===========================================================================
#define BK 32
#define PAD 68

__global__ __launch_bounds__(256) void scores_f32(
    const float* __restrict__ outp, const float* __restrict__ ctx,
    float* __restrict__ attn)
{
    __shared__ float As[BK][PAD];
    __shared__ float Bs[BK][PAD];
    const int b = blockIdx.z, oy = blockIdx.y, ix = blockIdx.x;
    const int tid = threadIdx.x;
    const int tx = tid & 15, ty = tid >> 4;
    const float* Abase = outp + ((size_t)b * 2048 + oy * 64) * 512;
    const float* Bbase = ctx  + ((size_t)b * 2048 + ix * 64) * 512;
    float acc[4][4] = {};
    for (int kk = 0; kk < 512; kk += BK) {
#pragma unroll
        for (int h = 0; h < 2; ++h) {
            const int f = tid + h * 256;
            const int row = f >> 3, k4 = f & 7;
            float4 a = *(const float4*)(Abase + (size_t)row * 512 + kk + k4 * 4);
            float4 c = *(const float4*)(Bbase + (size_t)row * 512 + kk + k4 * 4);
            As[k4 * 4 + 0][row] = a.x; As[k4 * 4 + 1][row] = a.y;
            As[k4 * 4 + 2][row] = a.z; As[k4 * 4 + 3][row] = a.w;
            Bs[k4 * 4 + 0][row] = c.x; Bs[k4 * 4 + 1][row] = c.y;
            Bs[k4 * 4 + 2][row] = c.z; Bs[k4 * 4 + 3][row] = c.w;
        }
        __syncthreads();
#pragma unroll
        for (int k = 0; k < BK; ++k) {
            float4 av = *(const float4*)&As[k][ty * 4];
            float4 bv = *(const float4*)&Bs[k][tx * 4];
            acc[0][0] += av.x * bv.x; acc[0][1] += av.x * bv.y; acc[0][2] += av.x * bv.z; acc[0][3] += av.x * bv.w;
            acc[1][0] += av.y * bv.x; acc[1][1] += av.y * bv.y; acc[1][2] += av.y * bv.z; acc[1][3] += av.y * bv.w;
            acc[2][0] += av.z * bv.x; acc[2][1] += av.z * bv.y; acc[2][2] += av.z * bv.z; acc[2][3] += av.z * bv.w;
            acc[3][0] += av.w * bv.x; acc[3][1] += av.w * bv.y; acc[3][2] += av.w * bv.z; acc[3][3] += av.w * bv.w;
        }
        __syncthreads();
    }
    float* dst = attn + ((size_t)b * 2048 + oy * 64 + ty * 4) * 2048 + ix * 64 + tx * 4;
#pragma unroll
    for (int i = 0; i < 4; ++i)
        *(float4*)(dst + (size_t)i * 2048) = make_float4(acc[i][0], acc[i][1], acc[i][2], acc[i][3]);
}

__global__ __launch_bounds__(256) void pv_f32(
    const float* __restrict__ attn, const float* __restrict__ ctx,
    float* __restrict__ mix)
{
    __shared__ float As[BK][PAD];
    __shared__ float Bs[BK][PAD];
    const int b = blockIdx.z, my = blockIdx.y, nx = blockIdx.x;
    const int tid = threadIdx.x;
    const int tx = tid & 15, ty = tid >> 4;
    const float* Abase = attn + ((size_t)b * 2048 + my * 64) * 2048;
    const float* Bbase = ctx  + ((size_t)b * 2048) * 512 + nx * 64;
    float acc[4][4] = {};
    for (int kk = 0; kk < 2048; kk += BK) {
#pragma unroll
        for (int h = 0; h < 2; ++h) {
            const int f = tid + h * 256;
            const int row = f >> 3, k4 = f & 7;
            float4 a = *(const float4*)(Abase + (size_t)row * 2048 + kk + k4 * 4);
            As[k4 * 4 + 0][row] = a.x; As[k4 * 4 + 1][row] = a.y;
            As[k4 * 4 + 2][row] = a.z; As[k4 * 4 + 3][row] = a.w;
            const int krow = f >> 4, col4 = f & 15;
            float4 c = *(const float4*)(Bbase + (size_t)(kk + krow) * 512 + col4 * 4);
            *(float4*)&Bs[krow][col4 * 4] = c;
        }
        __syncthreads();
#pragma unroll
        for (int k = 0; k < BK; ++k) {
            float4 av = *(const float4*)&As[k][ty * 4];
            float4 bv = *(const float4*)&Bs[k][tx * 4];
            acc[0][0] += av.x * bv.x; acc[0][1] += av.x * bv.y; acc[0][2] += av.x * bv.z; acc[0][3] += av.x * bv.w;
            acc[1][0] += av.y * bv.x; acc[1][1] += av.y * bv.y; acc[1][2] += av.y * bv.z; acc[1][3] += av.y * bv.w;
            acc[2][0] += av.z * bv.x; acc[2][1] += av.z * bv.y; acc[2][2] += av.z * bv.z; acc[2][3] += av.z * bv.w;
            acc[3][0] += av.w * bv.x; acc[3][1] += av.w * bv.y; acc[3][2] += av.w * bv.z; acc[3][3] += av.w * bv.w;
        }
        __syncthreads();
    }
    float* dst = mix + ((size_t)b * 2048 + my * 64 + ty * 4) * 512 + nx * 64 + tx * 4;
#pragma unroll
    for (int i = 0; i < 4; ++i)
        *(float4*)(dst + (size_t)i * 512) = make_float4(acc[i][0], acc[i][1], acc[i][2], acc[i][3]);
}

__global__ __launch_bounds__(256) void linear_f32(
    const float* __restrict__ mix, const float* __restrict__ outp,
    const float* __restrict__ Wm, const float* __restrict__ bias,
    float* __restrict__ dst)
{
    __shared__ float As[BK][PAD];
    __shared__ float Ws[BK][PAD];
    const int my = blockIdx.y, nx = blockIdx.x;
    const int tid = threadIdx.x;
    const int tx = tid & 15, ty = tid >> 4;
    const int m0 = my * 64, n0 = nx * 64;
    float acc[4][4] = {};
    for (int kk = 0; kk < 1024; kk += BK) {
        const float* Abase = (kk < 512) ? (mix + (size_t)m0 * 512 + kk)
                                        : (outp + (size_t)m0 * 512 + (kk - 512));
#pragma unroll
        for (int h = 0; h < 2; ++h) {
            const int f = tid + h * 256;
            const int row = f >> 3, k4 = f & 7;
            float4 a = *(const float4*)(Abase + (size_t)row * 512 + k4 * 4);
            As[k4 * 4 + 0][row] = a.x; As[k4 * 4 + 1][row] = a.y;
            As[k4 * 4 + 2][row] = a.z; As[k4 * 4 + 3][row] = a.w;
            float4 w = *(const float4*)(Wm + (size_t)(n0 + row) * 1024 + kk + k4 * 4);
            Ws[k4 * 4 + 0][row] = w.x; Ws[k4 * 4 + 1][row] = w.y;
            Ws[k4 * 4 + 2][row] = w.z; Ws[k4 * 4 + 3][row] = w.w;
        }
        __syncthreads();
#pragma unroll
        for (int k = 0; k < BK; ++k) {
            float4 av = *(const float4*)&As[k][ty * 4];
            float4 bv = *(const float4*)&Ws[k][tx * 4];
            acc[0][0] += av.x * bv.x; acc[0][1] += av.x * bv.y; acc[0][2] += av.x * bv.z; acc[0][3] += av.x * bv.w;
            acc[1][0] += av.y * bv.x; acc[1][1] += av.y * bv.y; acc[1][2] += av.y * bv.z; acc[1][3] += av.y * bv.w;
            acc[2][0] += av.z * bv.x; acc[2][1] += av.z * bv.y; acc[2][2] += av.z * bv.z; acc[2][3] += av.z * bv.w;
            acc[3][0] += av.w * bv.x; acc[3][1] += av.w * bv.y; acc[3][2] += av.w * bv.z; acc[3][3] += av.w * bv.w;
        }
        __syncthreads();
    }
#pragma unroll
    for (int i = 0; i < 4; ++i) {
        const int n = n0 + tx * 4;
        float4 bv = *(const float4*)(bias + n);
        float4 v;
        v.x = tanhf(acc[i][0] + bv.x); v.y = tanhf(acc[i][1] + bv.y);
        v.z = tanhf(acc[i][2] + bv.z); v.w = tanhf(acc[i][3] + bv.w);
        *(float4*)(dst + (size_t)(m0 + ty * 4 + i) * 512 + n) = v;
    }
}

// ===========================================================================
extern "C" void kernel_launch(void* const* d_in, const int* in_sizes, int n_in,
                              void* d_out, int out_size, void* d_ws, size_t ws_size,
                              hipStream_t stream) {
    const float* outp = (const float*)d_in[0];   // [8,2048,512]
    const float* ctx  = (const float*)d_in[1];   // [8,2048,512]
    const float* Wm   = (const float*)d_in[2];   // [512,1024]
    const float* bias = (const float*)d_in[3];   // [512]

    float* out  = (float*)d_out;
    float* attn = out + (size_t)8 * 2048 * 512;

    const size_t MB = 1ull << 20;
    const size_t NEED1 = 162 * MB;   // tier-1: +64MB attn_bf, mix aliases ctx
    const size_t NEED2 = 130 * MB;   // tier-2: round-1 layout

    if (ws_size >= NEED1) {
        char* w = (char*)d_ws;
        unsigned short* outp_hi = (unsigned short*)(w);              // 16MB
        unsigned short* outp_lo = (unsigned short*)(w + 16 * MB);
        unsigned short* ctx_hi  = (unsigned short*)(w + 32 * MB);
        unsigned short* ctx_lo  = (unsigned short*)(w + 48 * MB);
        unsigned short* ctxT_hi = (unsigned short*)(w + 64 * MB);
        unsigned short* ctxT_lo = (unsigned short*)(w + 80 * MB);
        unsigned short* W_hi    = (unsigned short*)(w + 96 * MB);
        unsigned short* W_lo    = (unsigned short*)(w + 97 * MB);
        unsigned short* attn_bf = (unsigned short*)(w + 98 * MB);    // 64MB
        // mix aliases ctx_hi/ctx_lo (ctx dead after scores)
        unsigned short* mix_hi  = ctx_hi;
        unsigned short* mix_lo  = ctx_lo;

        split_kernel<<<dim3(8192), 256, 0, stream>>>(outp, outp_hi, outp_lo);
        split_kernel<<<dim3(8192), 256, 0, stream>>>(ctx, ctx_hi, ctx_lo);
        split_kernel<<<dim3(512), 256, 0, stream>>>(Wm, W_hi, W_lo);
        transpose_split_kernel<<<dim3(16, 64, 8), 256, 0, stream>>>(ctx, ctxT_hi, ctxT_lo);

        scores_mfma8<<<dim3(512), 512, 0, stream>>>(outp_hi, outp_lo, ctx_hi, ctx_lo, attn);
        softmax_kernel<<<dim3(16384), 256, 0, stream>>>(attn, attn_bf);
        pv_mfma8<<<dim3(256), 512, 0, stream>>>(attn_bf, ctxT_hi, ctxT_lo, mix_hi, mix_lo);
        linear_mfma<<<dim3(512), 256, 0, stream>>>(mix_hi, mix_lo, outp_hi, outp_lo,
                                                   W_hi, W_lo, bias, out);
    } else if (ws_size >= NEED2) {
        char* w = (char*)d_ws;
        unsigned short* outp_hi = (unsigned short*)(w);
        unsigned short* outp_lo = (unsigned short*)(w + 16 * MB);
        unsigned short* ctx_hi  = (unsigned short*)(w + 32 * MB);
        unsigned short* ctx_lo  = (unsigned short*)(w + 48 * MB);
        unsigned short* ctxT_hi = (unsigned short*)(w + 64 * MB);
        unsigned short* ctxT_lo = (unsigned short*)(w + 80 * MB);
        unsigned short* W_hi    = (unsigned short*)(w + 96 * MB);
        unsigned short* W_lo    = (unsigned short*)(w + 97 * MB);
        unsigned short* mix_hi  = (unsigned short*)(w + 98 * MB);
        unsigned short* mix_lo  = (unsigned short*)(w + 114 * MB);

        split_kernel<<<dim3(8192), 256, 0, stream>>>(outp, outp_hi, outp_lo);
        split_kernel<<<dim3(8192), 256, 0, stream>>>(ctx, ctx_hi, ctx_lo);
        split_kernel<<<dim3(512), 256, 0, stream>>>(Wm, W_hi, W_lo);
        transpose_split_kernel<<<dim3(16, 64, 8), 256, 0, stream>>>(ctx, ctxT_hi, ctxT_lo);

        scores_mfma8<<<dim3(512), 512, 0, stream>>>(outp_hi, outp_lo, ctx_hi, ctx_lo, attn);
        softmax_kernel<<<dim3(16384), 256, 0, stream>>>(attn, nullptr);
        pv_mfma_cvt<<<dim3(512), 256, 0, stream>>>(attn, ctxT_hi, ctxT_lo, mix_hi, mix_lo);
        linear_mfma<<<dim3(512), 256, 0, stream>>>(mix_hi, mix_lo, outp_hi, outp_lo,
                                                   W_hi, W_lo, bias, out);
    } else {
        float* mix = (float*)d_ws;
        scores_f32<<<dim3(32, 32, 8), 256, 0, stream>>>(outp, ctx, attn);
        softmax_kernel<<<dim3(16384), 256, 0, stream>>>(attn, nullptr);
        pv_f32<<<dim3(8, 32, 8), 256, 0, stream>>>(attn, ctx, mix);
        linear_f32<<<dim3(8, 256), 256, 0, stream>>>(mix, outp, Wm, bias, out);
    }
}

// Round 5
// 495.630 us; speedup vs baseline: 1.0975x; 1.0029x over previous
//
#include <hip/hip_runtime.h>
#include <math.h>

// B=8, T_OUT=2048, T_IN=2048, D=512
// attn = softmax(outp @ ctx^T); mix = attn @ ctx; out = tanh([mix,outp] @ W^T + b)
// d_out = out (8.4M f32) ++ attn (33.6M f32)
//
// bf16 hi/lo split-MFMA emulation of f32 GEMMs (no fp32 MFMA on CDNA4).
// Round 5: linear ported to the overlap template (third application):
// BM=256 BN=128 BK=32, 8 waves, 96KiB LDS dbuf, swizzled subtiles,
// counted vmcnt(6), mid-step lgkm(0)+barrier, stage-2-ahead, source switch
// (mix->outp at k=512) folded into stage. scores/pv unchanged.

typedef short s8v __attribute__((ext_vector_type(8)));    // 8 bf16 (4 VGPR)
typedef float f4v __attribute__((ext_vector_type(4)));    // MFMA acc

__device__ __forceinline__ unsigned short f2bf(float f) {
    unsigned int u = __float_as_uint(f);
    u += 0x7fff + ((u >> 16) & 1);           // RNE
    return (unsigned short)(u >> 16);
}
__device__ __forceinline__ float bf2f(unsigned short h) {
    return __uint_as_float(((unsigned int)h) << 16);
}

__device__ __forceinline__ void async16(void* lds, const void* g) {
    __builtin_amdgcn_global_load_lds(
        (const __attribute__((address_space(1))) unsigned int*)g,
        (__attribute__((address_space(3))) unsigned int*)lds, 16, 0, 0);
}

__device__ __forceinline__ void phase_barrier() {
    asm volatile("" ::: "memory");
    __builtin_amdgcn_s_barrier();
    asm volatile("" ::: "memory");
}

// ---------------------------------------------------------------------------
// Prep: elementwise f32 -> bf16 hi/lo split
// ---------------------------------------------------------------------------
__global__ __launch_bounds__(256) void split_kernel(
    const float* __restrict__ src, unsigned short* __restrict__ hi,
    unsigned short* __restrict__ lo)
{
    const size_t i = ((size_t)blockIdx.x * 256 + threadIdx.x) * 4;
    float4 v = *(const float4*)(src + i);
    ushort4 h, l;
    h.x = f2bf(v.x); l.x = f2bf(v.x - bf2f(h.x));
    h.y = f2bf(v.y); l.y = f2bf(v.y - bf2f(h.y));
    h.z = f2bf(v.z); l.z = f2bf(v.z - bf2f(h.z));
    h.w = f2bf(v.w); l.w = f2bf(v.w - bf2f(h.w));
    *(ushort4*)(hi + i) = h;
    *(ushort4*)(lo + i) = l;
}

// ---------------------------------------------------------------------------
// Prep: ctx[b][i][d] f32 -> ctxT_hi/lo[b][d][i] bf16
// ---------------------------------------------------------------------------
__global__ __launch_bounds__(256) void transpose_split_kernel(
    const float* __restrict__ ctx, unsigned short* __restrict__ tHi,
    unsigned short* __restrict__ tLo)
{
    __shared__ float tile[32][33];
    const int b = blockIdx.z, i0 = blockIdx.y * 32, d0 = blockIdx.x * 32;
    const int t = threadIdx.x;
    {
        const int il = t >> 3, d4 = t & 7;
        float4 v = *(const float4*)(ctx + ((size_t)b * 2048 + i0 + il) * 512 + d0 + d4 * 4);
        tile[il][d4 * 4 + 0] = v.x; tile[il][d4 * 4 + 1] = v.y;
        tile[il][d4 * 4 + 2] = v.z; tile[il][d4 * 4 + 3] = v.w;
    }
    __syncthreads();
    {
        const int dl = t >> 3, i4 = t & 7;
        ushort4 h, l;
        float v0 = tile[i4 * 4 + 0][dl], v1 = tile[i4 * 4 + 1][dl];
        float v2 = tile[i4 * 4 + 2][dl], v3 = tile[i4 * 4 + 3][dl];
        h.x = f2bf(v0); l.x = f2bf(v0 - bf2f(h.x));
        h.y = f2bf(v1); l.y = f2bf(v1 - bf2f(h.y));
        h.z = f2bf(v2); l.z = f2bf(v2 - bf2f(h.z));
        h.w = f2bf(v3); l.w = f2bf(v3 - bf2f(h.w));
        const size_t o = ((size_t)b * 512 + d0 + dl) * 2048 + i0 + i4 * 4;
        *(ushort4*)(tHi + o) = h;
        *(ushort4*)(tLo + o) = l;
    }
}

// ---------------------------------------------------------------------------
// Scores (round-2, kept): 256x256 tile, BK=32, 8 waves, split-3 MFMA,
// 2-barrier overlap schedule, counted vmcnt(8), swizzled LDS (0 conflicts).
// ---------------------------------------------------------------------------
__global__ __launch_bounds__(512, 2) void scores_mfma8(
    const unsigned short* __restrict__ Agh, const unsigned short* __restrict__ Agl,
    const unsigned short* __restrict__ Bgh, const unsigned short* __restrict__ Bgl,
    float* __restrict__ attn)
{
    __shared__ __attribute__((aligned(16))) unsigned short S[65536];  // 128 KiB

    const int id = blockIdx.x;
    const int b = id & 7, seq = id >> 3;
    const int ix = seq & 7, oy = seq >> 3;
    const int tid = threadIdx.x;
    const int wave = tid >> 6, lane = tid & 63;
    const int wr = wave >> 2, wc = wave & 3;       // wave tile: rows wr*128, cols wc*64
    const int c16 = lane & 15;
    // swizzled read chunk: q ^ row[2:1]
    const int sq8 = (((lane >> 4) ^ ((c16 >> 1) & 3)) << 3);
    const int aBase = (wr * 128 + c16) * 32 + sq8;
    const int bBase = (wc * 64 + c16) * 32 + sq8;

    // staging: per issue, 512 threads cover 128 rows x 32 shorts (8 KB)
    const int srow = lane >> 2;
    const int kswz = (((lane & 3) ^ ((lane >> 3) & 3)) << 3);   // pre-swizzled source chunk
    const int ldsW = wave * 512;                                 // wave*16 rows * 32 shorts
    const size_t gA = (size_t)(b * 2048 + oy * 256 + wave * 16 + srow) * 512 + kswz;
    const size_t gB = (size_t)(b * 2048 + ix * 256 + wave * 16 + srow) * 512 + kswz;

    auto stageB = [&](int s) {
        unsigned short* D = &S[(s & 1) << 15];
        const int kks = s << 5;
        async16(&D[16384 + ldsW], Bgh + gB + kks);
        async16(&D[20480 + ldsW], Bgh + gB + 65536 + kks);
        async16(&D[24576 + ldsW], Bgl + gB + kks);
        async16(&D[28672 + ldsW], Bgl + gB + 65536 + kks);
    };
    auto stageA = [&](int s) {
        unsigned short* D = &S[(s & 1) << 15];
        const int kks = s << 5;
        async16(&D[0 + ldsW],     Agh + gA + kks);
        async16(&D[4096 + ldsW],  Agh + gA + 65536 + kks);
        async16(&D[8192 + ldsW],  Agl + gA + kks);
        async16(&D[12288 + ldsW], Agl + gA + 65536 + kks);
    };

    f4v acc[8][4];
#pragma unroll
    for (int i = 0; i < 8; ++i)
#pragma unroll
        for (int j = 0; j < 4; ++j) acc[i][j] = (f4v)0.0f;

    // prologue: stage K-steps 0 and 1; wait step 0 (8 newest = step 1 in flight)
    stageB(0); stageA(0);
    stageB(1); stageA(1);
    asm volatile("s_waitcnt vmcnt(8)" ::: "memory");
    phase_barrier();

    // B(0) frags (held in regs across each K-step)
    s8v bh[4], bl[4];
#pragma unroll
    for (int n = 0; n < 4; ++n) {
        bh[n] = *(const s8v*)&S[16384 + bBase + n * 512];
        bl[n] = *(const s8v*)&S[24576 + bBase + n * 512];
    }

    for (int t = 0; t < 16; ++t) {
        const unsigned short* Sb = &S[(t & 1) << 15];
        s8v ah0[4], al0[4], ah1[4], al1[4];

        // issue A0 reads (rows m0..3 of wave tile)
#pragma unroll
        for (int m = 0; m < 4; ++m) {
            ah0[m] = *(const s8v*)&Sb[aBase + m * 512];
            al0[m] = *(const s8v*)&Sb[8192 + aBase + m * 512];
        }
        // Q0: A0 x B0 (n=0,1)
        __builtin_amdgcn_s_setprio(1);
#pragma unroll
        for (int m = 0; m < 4; ++m)
#pragma unroll
            for (int n = 0; n < 2; ++n) {
                acc[m][n] = __builtin_amdgcn_mfma_f32_16x16x32_bf16(ah0[m], bh[n], acc[m][n], 0, 0, 0);
                acc[m][n] = __builtin_amdgcn_mfma_f32_16x16x32_bf16(ah0[m], bl[n], acc[m][n], 0, 0, 0);
                acc[m][n] = __builtin_amdgcn_mfma_f32_16x16x32_bf16(al0[m], bh[n], acc[m][n], 0, 0, 0);
            }
        __builtin_amdgcn_s_setprio(0);

        // issue A1 reads (rows m4..7) — overlap with Q1's MFMAs
#pragma unroll
        for (int m = 0; m < 4; ++m) {
            ah1[m] = *(const s8v*)&Sb[aBase + 2048 + m * 512];
            al1[m] = *(const s8v*)&Sb[8192 + aBase + 2048 + m * 512];
        }
        // Q1: A0 x B1 (n=2,3)
        __builtin_amdgcn_s_setprio(1);
#pragma unroll
        for (int m = 0; m < 4; ++m)
#pragma unroll
            for (int n = 2; n < 4; ++n) {
                acc[m][n] = __builtin_amdgcn_mfma_f32_16x16x32_bf16(ah0[m], bh[n], acc[m][n], 0, 0, 0);
                acc[m][n] = __builtin_amdgcn_mfma_f32_16x16x32_bf16(ah0[m], bl[n], acc[m][n], 0, 0, 0);
                acc[m][n] = __builtin_amdgcn_mfma_f32_16x16x32_bf16(al0[m], bh[n], acc[m][n], 0, 0, 0);
            }
        __builtin_amdgcn_s_setprio(0);

        // all reads of buf[t&1] must retire before other waves' DMA overwrites
        asm volatile("s_waitcnt lgkmcnt(0)" ::: "memory");
        __builtin_amdgcn_sched_barrier(0);
        phase_barrier();

        // stage K-step t+2 into buf[t&1] (just fully consumed)
        if (t < 14) { stageB(t + 2); stageA(t + 2); }

        // Q2: A1 x B0 — overlaps stage issue
        __builtin_amdgcn_s_setprio(1);
#pragma unroll
        for (int m = 0; m < 4; ++m)
#pragma unroll
            for (int n = 0; n < 2; ++n) {
                acc[m + 4][n] = __builtin_amdgcn_mfma_f32_16x16x32_bf16(ah1[m], bh[n], acc[m + 4][n], 0, 0, 0);
                acc[m + 4][n] = __builtin_amdgcn_mfma_f32_16x16x32_bf16(ah1[m], bl[n], acc[m + 4][n], 0, 0, 0);
                acc[m + 4][n] = __builtin_amdgcn_mfma_f32_16x16x32_bf16(al1[m], bh[n], acc[m + 4][n], 0, 0, 0);
            }
        __builtin_amdgcn_s_setprio(0);

        // counted wait: K-step t+1's loads landed (t+2's 8 stay in flight)
        if (t < 14) {
            asm volatile("s_waitcnt vmcnt(8)" ::: "memory");
        } else if (t == 14) {
            asm volatile("s_waitcnt vmcnt(0)" ::: "memory");
        }
        phase_barrier();

        // issue B(t+1) reads from the now-ready buffer — overlap with Q3
        s8v nbh[4], nbl[4];
        if (t < 15) {
            const unsigned short* Sn = &S[((t + 1) & 1) << 15];
#pragma unroll
            for (int n = 0; n < 4; ++n) {
                nbh[n] = *(const s8v*)&Sn[16384 + bBase + n * 512];
                nbl[n] = *(const s8v*)&Sn[24576 + bBase + n * 512];
            }
        }
        // Q3: A1 x B1
        __builtin_amdgcn_s_setprio(1);
#pragma unroll
        for (int m = 0; m < 4; ++m)
#pragma unroll
            for (int n = 2; n < 4; ++n) {
                acc[m + 4][n] = __builtin_amdgcn_mfma_f32_16x16x32_bf16(ah1[m], bh[n], acc[m + 4][n], 0, 0, 0);
                acc[m + 4][n] = __builtin_amdgcn_mfma_f32_16x16x32_bf16(ah1[m], bl[n], acc[m + 4][n], 0, 0, 0);
                acc[m + 4][n] = __builtin_amdgcn_mfma_f32_16x16x32_bf16(al1[m], bh[n], acc[m + 4][n], 0, 0, 0);
            }
        __builtin_amdgcn_s_setprio(0);

        if (t < 15) {
#pragma unroll
            for (int n = 0; n < 4; ++n) { bh[n] = nbh[n]; bl[n] = nbl[n]; }
        }
    }

    float* dst = attn + ((size_t)(b * 2048 + oy * 256 + wr * 128)) * 2048 + ix * 256 + wc * 64;
    const int q4 = (lane >> 4) * 4;
#pragma unroll
    for (int mt = 0; mt < 8; ++mt)
#pragma unroll
        for (int nt = 0; nt < 4; ++nt)
#pragma unroll
            for (int r = 0; r < 4; ++r)
                dst[(size_t)(mt * 16 + q4 + r) * 2048 + nt * 16 + c16] = acc[mt][nt][r];
}

// ---------------------------------------------------------------------------
// Softmax: in-place; optionally emits bf16 copy of the final probabilities.
// ---------------------------------------------------------------------------
__global__ __launch_bounds__(256) void softmax_kernel(
    float* __restrict__ attn, unsigned short* __restrict__ attn_bf)
{
    const size_t base = (size_t)blockIdx.x * 2048;
    const int tid = threadIdx.x;
    float4 v0 = *(float4*)(attn + base + tid * 4);
    float4 v1 = *(float4*)(attn + base + 1024 + tid * 4);

    float mx = fmaxf(fmaxf(fmaxf(v0.x, v0.y), fmaxf(v0.z, v0.w)),
                     fmaxf(fmaxf(v1.x, v1.y), fmaxf(v1.z, v1.w)));
#pragma unroll
    for (int off = 32; off > 0; off >>= 1) mx = fmaxf(mx, __shfl_down(mx, off));

    __shared__ float red[4];
    const int wave = tid >> 6, lane = tid & 63;
    if (lane == 0) red[wave] = mx;
    __syncthreads();
    if (tid == 0) red[0] = fmaxf(fmaxf(red[0], red[1]), fmaxf(red[2], red[3]));
    __syncthreads();
    mx = red[0];
    __syncthreads();

    v0.x = expf(v0.x - mx); v0.y = expf(v0.y - mx);
    v0.z = expf(v0.z - mx); v0.w = expf(v0.w - mx);
    v1.x = expf(v1.x - mx); v1.y = expf(v1.y - mx);
    v1.z = expf(v1.z - mx); v1.w = expf(v1.w - mx);

    float s = v0.x + v0.y + v0.z + v0.w + v1.x + v1.y + v1.z + v1.w;
#pragma unroll
    for (int off = 32; off > 0; off >>= 1) s += __shfl_down(s, off);
    if (lane == 0) red[wave] = s;
    __syncthreads();
    if (tid == 0) red[0] = red[0] + red[1] + red[2] + red[3];
    __syncthreads();
    const float inv = 1.0f / red[0];

    v0.x *= inv; v0.y *= inv; v0.z *= inv; v0.w *= inv;
    v1.x *= inv; v1.y *= inv; v1.z *= inv; v1.w *= inv;
    *(float4*)(attn + base + tid * 4) = v0;
    *(float4*)(attn + base + 1024 + tid * 4) = v1;

    if (attn_bf) {
        ushort4 h0, h1;
        h0.x = f2bf(v0.x); h0.y = f2bf(v0.y); h0.z = f2bf(v0.z); h0.w = f2bf(v0.w);
        h1.x = f2bf(v1.x); h1.y = f2bf(v1.y); h1.z = f2bf(v1.z); h1.w = f2bf(v1.w);
        *(ushort4*)(attn_bf + base + tid * 4) = h0;
        *(ushort4*)(attn_bf + base + 1024 + tid * 4) = h1;
    }
}

// ---------------------------------------------------------------------------
// PV (round-3/4, kept): BM=256, BN=128, BK=64 (2 k-slices of 32), 8 waves,
// A = attn_bf (bf16 single), B = ctxT hi/lo (2-MFMA). 128KiB dbuf, vmcnt(8).
// ---------------------------------------------------------------------------
__global__ __launch_bounds__(512, 2) void pv_mfma8(
    const unsigned short* __restrict__ attn_bf,
    const unsigned short* __restrict__ Bgh, const unsigned short* __restrict__ Bgl,
    unsigned short* __restrict__ mixHi, unsigned short* __restrict__ mixLo)
{
    __shared__ __attribute__((aligned(16))) unsigned short S[65536];  // 128 KiB

    const int id = blockIdx.x;
    const int b = id & 7, seq = id >> 3;
    const int nx = seq & 3, my = seq >> 2;         // my 0..7, nx 0..3
    const int tid = threadIdx.x;
    const int wave = tid >> 6, lane = tid & 63;
    const int wr = wave >> 2, wc = wave & 3;       // rows wr*128, cols wc*32
    const int c16 = lane & 15;
    const int sq8 = (((lane >> 4) ^ ((c16 >> 1) & 3)) << 3);
    const int aBase = (wr * 128 + c16) * 32 + sq8;  // within A slice tile [256][32]
    const int bBase = (wc * 32 + c16) * 32 + sq8;   // within B slice tile [128][32]

    const int srow = lane >> 2;
    const int kswz = (((lane & 3) ^ ((lane >> 3) & 3)) << 3);
    const int ldsW = wave * 512;                    // wave*16 rows * 32 shorts

    const size_t gA = (size_t)(b * 2048 + my * 256 + wave * 16 + srow) * 2048 + kswz;
    const size_t gB = (size_t)(b * 512 + nx * 128 + wave * 16 + srow) * 2048 + kswz;

    auto stage = [&](int t) {
        unsigned short* D = &S[(t & 1) << 15];
        const int kk = t << 6;
        // A slices: s*8192, halves: h*4096
        async16(&D[0 + ldsW],            attn_bf + gA + kk);                    // s0 h0
        async16(&D[4096 + ldsW],         attn_bf + gA + (size_t)128 * 2048 + kk);       // s0 h1
        async16(&D[8192 + ldsW],         attn_bf + gA + kk + 32);               // s1 h0
        async16(&D[12288 + ldsW],        attn_bf + gA + (size_t)128 * 2048 + kk + 32);  // s1 h1
        // B: Bh slices @16384 + s*4096, Bl @24576 + s*4096
        async16(&D[16384 + ldsW],        Bgh + gB + kk);
        async16(&D[16384 + 4096 + ldsW], Bgh + gB + kk + 32);
        async16(&D[24576 + ldsW],        Bgl + gB + kk);
        async16(&D[24576 + 4096 + ldsW], Bgl + gB + kk + 32);
    };

    f4v acc[8][2];
#pragma unroll
    for (int i = 0; i < 8; ++i)
#pragma unroll
        for (int j = 0; j < 2; ++j) acc[i][j] = (f4v)0.0f;

    // prologue: stage steps 0,1; wait step 0 (step-1's 8 stay in flight)
    stage(0); stage(1);
    asm volatile("s_waitcnt vmcnt(8)" ::: "memory");
    phase_barrier();

    for (int t = 0; t < 32; ++t) {
        const unsigned short* Sb = &S[(t & 1) << 15];
        s8v a0[4], a1[4], bhf[2], blf[2];

        // ---- slice 0 ----
#pragma unroll
        for (int m = 0; m < 4; ++m) a0[m] = *(const s8v*)&Sb[aBase + m * 512];
#pragma unroll
        for (int n = 0; n < 2; ++n) {
            bhf[n] = *(const s8v*)&Sb[16384 + bBase + n * 512];
            blf[n] = *(const s8v*)&Sb[24576 + bBase + n * 512];
        }
        // Q0: slice0, m0..3
        __builtin_amdgcn_s_setprio(1);
#pragma unroll
        for (int m = 0; m < 4; ++m)
#pragma unroll
            for (int n = 0; n < 2; ++n) {
                acc[m][n] = __builtin_amdgcn_mfma_f32_16x16x32_bf16(a0[m], bhf[n], acc[m][n], 0, 0, 0);
                acc[m][n] = __builtin_amdgcn_mfma_f32_16x16x32_bf16(a0[m], blf[n], acc[m][n], 0, 0, 0);
            }
        __builtin_amdgcn_s_setprio(0);
        // A1 slice0 (rows m4..7)
#pragma unroll
        for (int m = 0; m < 4; ++m) a1[m] = *(const s8v*)&Sb[aBase + 2048 + m * 512];
        // Q1: slice0, m4..7
        __builtin_amdgcn_s_setprio(1);
#pragma unroll
        for (int m = 0; m < 4; ++m)
#pragma unroll
            for (int n = 0; n < 2; ++n) {
                acc[m + 4][n] = __builtin_amdgcn_mfma_f32_16x16x32_bf16(a1[m], bhf[n], acc[m + 4][n], 0, 0, 0);
                acc[m + 4][n] = __builtin_amdgcn_mfma_f32_16x16x32_bf16(a1[m], blf[n], acc[m + 4][n], 0, 0, 0);
            }
        __builtin_amdgcn_s_setprio(0);

        // ---- slice 1 ----
#pragma unroll
        for (int m = 0; m < 4; ++m) a0[m] = *(const s8v*)&Sb[8192 + aBase + m * 512];
#pragma unroll
        for (int n = 0; n < 2; ++n) {
            bhf[n] = *(const s8v*)&Sb[16384 + 4096 + bBase + n * 512];
            blf[n] = *(const s8v*)&Sb[24576 + 4096 + bBase + n * 512];
        }
        // Q2: slice1, m0..3
        __builtin_amdgcn_s_setprio(1);
#pragma unroll
        for (int m = 0; m < 4; ++m)
#pragma unroll
            for (int n = 0; n < 2; ++n) {
                acc[m][n] = __builtin_amdgcn_mfma_f32_16x16x32_bf16(a0[m], bhf[n], acc[m][n], 0, 0, 0);
                acc[m][n] = __builtin_amdgcn_mfma_f32_16x16x32_bf16(a0[m], blf[n], acc[m][n], 0, 0, 0);
            }
        __builtin_amdgcn_s_setprio(0);
        // A1 slice1
#pragma unroll
        for (int m = 0; m < 4; ++m) a1[m] = *(const s8v*)&Sb[8192 + aBase + 2048 + m * 512];

        // all reads of buf[t&1] retired before DMA overwrite
        asm volatile("s_waitcnt lgkmcnt(0)" ::: "memory");
        __builtin_amdgcn_sched_barrier(0);
        phase_barrier();

        if (t < 30) stage(t + 2);

        // Q3: slice1, m4..7 — overlaps stage issue
        __builtin_amdgcn_s_setprio(1);
#pragma unroll
        for (int m = 0; m < 4; ++m)
#pragma unroll
            for (int n = 0; n < 2; ++n) {
                acc[m + 4][n] = __builtin_amdgcn_mfma_f32_16x16x32_bf16(a1[m], bhf[n], acc[m + 4][n], 0, 0, 0);
                acc[m + 4][n] = __builtin_amdgcn_mfma_f32_16x16x32_bf16(a1[m], blf[n], acc[m + 4][n], 0, 0, 0);
            }
        __builtin_amdgcn_s_setprio(0);

        if (t < 30) {
            asm volatile("s_waitcnt vmcnt(8)" ::: "memory");
        } else if (t == 30) {
            asm volatile("s_waitcnt vmcnt(0)" ::: "memory");
        }
        phase_barrier();
    }

    const int q4 = (lane >> 4) * 4;
    const size_t mrow = (size_t)(b * 2048 + my * 256 + wr * 128);
#pragma unroll
    for (int mt = 0; mt < 8; ++mt)
#pragma unroll
        for (int nt = 0; nt < 2; ++nt) {
            const int col = nx * 128 + wc * 32 + nt * 16 + c16;
#pragma unroll
            for (int r = 0; r < 4; ++r) {
                float v = acc[mt][nt][r];
                unsigned short h = f2bf(v);
                unsigned short l = f2bf(v - bf2f(h));
                const size_t o = (mrow + mt * 16 + q4 + r) * 512 + col;
                mixHi[o] = h; mixLo[o] = l;
            }
        }
}

// ---------------------------------------------------------------------------
// PV tier-2 (round-1 structure + swizzle): A = f32 attn converted inline.
// ---------------------------------------------------------------------------
__global__ __launch_bounds__(256) void pv_mfma_cvt(
    const float* __restrict__ attn,
    const unsigned short* __restrict__ Bgh, const unsigned short* __restrict__ Bgl,
    unsigned short* __restrict__ mixHi, unsigned short* __restrict__ mixLo)
{
    __shared__ __attribute__((aligned(16))) unsigned short Ab[128 * 32],
                                                           Bh[128 * 32], Bl[128 * 32];
    const int id = blockIdx.x;
    const int b = id & 7, seq = id >> 3;
    const int nx = seq & 3, my = seq >> 2;
    const int tid = threadIdx.x, wave = tid >> 6, lane = tid & 63;
    const int wm = wave >> 1, wn = wave & 1;
    const int c16 = lane & 15, q8 = (lane >> 4) * 8;

    const float* Abase = attn + ((size_t)b * 2048 + my * 128) * 2048;
    const size_t brow = (size_t)(b * 512 + nx * 128);

    f4v acc[4][4];
#pragma unroll
    for (int i = 0; i < 4; ++i)
#pragma unroll
        for (int j = 0; j < 4; ++j) acc[i][j] = (f4v)0.0f;

    for (int kk = 0; kk < 2048; kk += 32) {
#pragma unroll
        for (int it = 0; it < 4; ++it) {
            const int idx = tid + it * 256;
            const int r = idx >> 3, kc = idx & 7;
            float4 v = *(const float4*)(Abase + (size_t)r * 2048 + kk + kc * 4);
            ushort4 h;
            h.x = f2bf(v.x); h.y = f2bf(v.y); h.z = f2bf(v.z); h.w = f2bf(v.w);
            *(ushort4*)&Ab[r * 32 + kc * 4] = h;
        }
#pragma unroll
        for (int it = 0; it < 2; ++it) {
            const int r0 = it * 64 + wave * 16;
            const size_t gb = (brow + r0 + (lane >> 2)) * 2048 + kk + (lane & 3) * 8;
            async16(&Bh[r0 * 32], Bgh + gb);
            async16(&Bl[r0 * 32], Bgl + gb);
        }
        __syncthreads();
        s8v ab[4], bh[4], bl[4];
#pragma unroll
        for (int t = 0; t < 4; ++t) {
            ab[t] = *(const s8v*)&Ab[(wm * 64 + t * 16 + c16) * 32 + q8];
            bh[t] = *(const s8v*)&Bh[(wn * 64 + t * 16 + c16) * 32 + q8];
            bl[t] = *(const s8v*)&Bl[(wn * 64 + t * 16 + c16) * 32 + q8];
        }
#pragma unroll
        for (int mt = 0; mt < 4; ++mt)
#pragma unroll
            for (int nt = 0; nt < 4; ++nt) {
                acc[mt][nt] = __builtin_amdgcn_mfma_f32_16x16x32_bf16(ab[mt], bh[nt], acc[mt][nt], 0, 0, 0);
                acc[mt][nt] = __builtin_amdgcn_mfma_f32_16x16x32_bf16(ab[mt], bl[nt], acc[mt][nt], 0, 0, 0);
            }
        __syncthreads();
    }
    const int q4 = (lane >> 4) * 4;
    const size_t mrow = (size_t)(b * 2048 + my * 128 + wm * 64);
#pragma unroll
    for (int mt = 0; mt < 4; ++mt)
#pragma unroll
        for (int nt = 0; nt < 4; ++nt) {
            const int col = nx * 128 + wn * 64 + nt * 16 + c16;
#pragma unroll
            for (int r = 0; r < 4; ++r) {
                float v = acc[mt][nt][r];
                unsigned short h = f2bf(v);
                unsigned short l = f2bf(v - bf2f(h));
                const size_t o = (mrow + mt * 16 + q4 + r) * 512 + col;
                mixHi[o] = h; mixLo[o] = l;
            }
        }
}

// ---------------------------------------------------------------------------
// Linear v2: overlap template. BM=256, BN=128, BK=32, 32 K-steps,
// 8 waves (2x4, wave tile 128x32, acc[8][2]), split-3 MFMA.
// LDS per buffer (shorts): Ah [256][32] @0, Al @8192, Bh [128][32] @16384,
// Bl @20480; buffer stride 24576 (96 KiB total dbuf). 6 async issues/step ->
// counted vmcnt(6). Source switch mix->outp at step 16 inside stage().
// Grid 256: nx = id&3, my = id>>2. Fused bias+tanh epilogue.
// ---------------------------------------------------------------------------
__global__ __launch_bounds__(512, 2) void linear_mfma8(
    const unsigned short* __restrict__ mixHi, const unsigned short* __restrict__ mixLo,
    const unsigned short* __restrict__ outHi, const unsigned short* __restrict__ outLo,
    const unsigned short* __restrict__ Wh, const unsigned short* __restrict__ Wl,
    const float* __restrict__ bias, float* __restrict__ dst)
{
    __shared__ __attribute__((aligned(16))) unsigned short S[49152];  // 96 KiB

    const int id = blockIdx.x;
    const int nx = id & 3, my = id >> 2;           // my 0..63, nx 0..3
    const int tid = threadIdx.x;
    const int wave = tid >> 6, lane = tid & 63;
    const int wr = wave >> 2, wc = wave & 3;       // rows wr*128, cols wc*32
    const int c16 = lane & 15;
    const int sq8 = (((lane >> 4) ^ ((c16 >> 1) & 3)) << 3);
    const int aBase = (wr * 128 + c16) * 32 + sq8;  // within A tile [256][32]
    const int bBase = (wc * 32 + c16) * 32 + sq8;   // within B tile [128][32]

    const int srow = lane >> 2;
    const int kswz = (((lane & 3) ^ ((lane >> 3) & 3)) << 3);
    const int ldsW = wave * 512;                    // wave*16 rows * 32 shorts

    const size_t gA = (size_t)(my * 256 + wave * 16 + srow) * 512 + kswz;
    const size_t gW = (size_t)(nx * 128 + wave * 16 + srow) * 1024 + kswz;

    auto stage = [&](int s) {
        unsigned short* D = &S[(s & 1) * 24576];
        const unsigned short* ah_src = (s < 16) ? mixHi : outHi;
        const unsigned short* al_src = (s < 16) ? mixLo : outLo;
        const int kc0 = (s & 15) << 5;
        const int kw = s << 5;
        async16(&D[0 + ldsW],     ah_src + gA + kc0);                       // A hi rows 0-127
        async16(&D[4096 + ldsW],  ah_src + gA + (size_t)128 * 512 + kc0);   // A hi rows 128-255
        async16(&D[8192 + ldsW],  al_src + gA + kc0);
        async16(&D[12288 + ldsW], al_src + gA + (size_t)128 * 512 + kc0);
        async16(&D[16384 + ldsW], Wh + gW + kw);
        async16(&D[20480 + ldsW], Wl + gW + kw);
    };

    f4v acc[8][2];
#pragma unroll
    for (int i = 0; i < 8; ++i)
#pragma unroll
        for (int j = 0; j < 2; ++j) acc[i][j] = (f4v)0.0f;

    // prologue: stage steps 0,1 (12 outstanding); wait step 0 (6 in flight)
    stage(0); stage(1);
    asm volatile("s_waitcnt vmcnt(6)" ::: "memory");
    phase_barrier();

    for (int t = 0; t < 32; ++t) {
        const unsigned short* Sb = &S[(t & 1) * 24576];
        s8v ah0[4], al0[4], ah1[4], al1[4], bh[2], bl[2];

        // issue A0 (rows m0..3) + B reads
#pragma unroll
        for (int m = 0; m < 4; ++m) {
            ah0[m] = *(const s8v*)&Sb[aBase + m * 512];
            al0[m] = *(const s8v*)&Sb[8192 + aBase + m * 512];
        }
#pragma unroll
        for (int n = 0; n < 2; ++n) {
            bh[n] = *(const s8v*)&Sb[16384 + bBase + n * 512];
            bl[n] = *(const s8v*)&Sb[20480 + bBase + n * 512];
        }
        // Q0: m0..3 x n0..1 (split-3, 24 MFMA)
        __builtin_amdgcn_s_setprio(1);
#pragma unroll
        for (int m = 0; m < 4; ++m)
#pragma unroll
            for (int n = 0; n < 2; ++n) {
                acc[m][n] = __builtin_amdgcn_mfma_f32_16x16x32_bf16(ah0[m], bh[n], acc[m][n], 0, 0, 0);
                acc[m][n] = __builtin_amdgcn_mfma_f32_16x16x32_bf16(ah0[m], bl[n], acc[m][n], 0, 0, 0);
                acc[m][n] = __builtin_amdgcn_mfma_f32_16x16x32_bf16(al0[m], bh[n], acc[m][n], 0, 0, 0);
            }
        __builtin_amdgcn_s_setprio(0);

        // issue A1 (rows m4..7)
#pragma unroll
        for (int m = 0; m < 4; ++m) {
            ah1[m] = *(const s8v*)&Sb[aBase + 2048 + m * 512];
            al1[m] = *(const s8v*)&Sb[8192 + aBase + 2048 + m * 512];
        }

        // all reads of buf[t&1] retired before DMA overwrite
        asm volatile("s_waitcnt lgkmcnt(0)" ::: "memory");
        __builtin_amdgcn_sched_barrier(0);
        phase_barrier();

        if (t < 30) stage(t + 2);

        // Q1: m4..7 x n0..1 — overlaps stage issue
        __builtin_amdgcn_s_setprio(1);
#pragma unroll
        for (int m = 0; m < 4; ++m)
#pragma unroll
            for (int n = 0; n < 2; ++n) {
                acc[m + 4][n] = __builtin_amdgcn_mfma_f32_16x16x32_bf16(ah1[m], bh[n], acc[m + 4][n], 0, 0, 0);
                acc[m + 4][n] = __builtin_amdgcn_mfma_f32_16x16x32_bf16(ah1[m], bl[n], acc[m + 4][n], 0, 0, 0);
                acc[m + 4][n] = __builtin_amdgcn_mfma_f32_16x16x32_bf16(al1[m], bh[n], acc[m + 4][n], 0, 0, 0);
            }
        __builtin_amdgcn_s_setprio(0);

        if (t < 30) {
            asm volatile("s_waitcnt vmcnt(6)" ::: "memory");
        } else if (t == 30) {
            asm volatile("s_waitcnt vmcnt(0)" ::: "memory");
        }
        phase_barrier();
    }

    const int q4 = (lane >> 4) * 4;
    const int mrow = my * 256 + wr * 128;
#pragma unroll
    for (int mt = 0; mt < 8; ++mt)
#pragma unroll
        for (int nt = 0; nt < 2; ++nt) {
            const int col = nx * 128 + wc * 32 + nt * 16 + c16;
            const float bb = bias[col];
#pragma unroll
            for (int r = 0; r < 4; ++r) {
                const size_t row = (size_t)(mrow + mt * 16 + q4 + r);
                dst[row * 512 + col] = tanhf(acc[mt][nt][r] + bb);
            }
        }
}

// ===========================================================================
// Fallback f32 path
// ===========================================================================
#define BK 32
#define PAD 68

__global__ __launch_bounds__(256) void scores_f32(
    const float* __restrict__ outp, const float* __restrict__ ctx,
    float* __restrict__ attn)
{
    __shared__ float As[BK][PAD];
    __shared__ float Bs[BK][PAD];
    const int b = blockIdx.z, oy = blockIdx.y, ix = blockIdx.x;
    const int tid = threadIdx.x;
    const int tx = tid & 15, ty = tid >> 4;
    const float* Abase = outp + ((size_t)b * 2048 + oy * 64) * 512;
    const float* Bbase = ctx  + ((size_t)b * 2048 + ix * 64) * 512;
    float acc[4][4] = {};
    for (int kk = 0; kk < 512; kk += BK) {
#pragma unroll
        for (int h = 0; h < 2; ++h) {
            const int f = tid + h * 256;
            const int row = f >> 3, k4 = f & 7;
            float4 a = *(const float4*)(Abase + (size_t)row * 512 + kk + k4 * 4);
            float4 c = *(const float4*)(Bbase + (size_t)row * 512 + kk + k4 * 4);
            As[k4 * 4 + 0][row] = a.x; As[k4 * 4 + 1][row] = a.y;
            As[k4 * 4 + 2][row] = a.z; As[k4 * 4 + 3][row] = a.w;
            Bs[k4 * 4 + 0][row] = c.x; Bs[k4 * 4 + 1][row] = c.y;
            Bs[k4 * 4 + 2][row] = c.z; Bs[k4 * 4 + 3][row] = c.w;
        }
        __syncthreads();
#pragma unroll
        for (int k = 0; k < BK; ++k) {
            float4 av = *(const float4*)&As[k][ty * 4];
            float4 bv = *(const float4*)&Bs[k][tx * 4];
            acc[0][0] += av.x * bv.x; acc[0][1] += av.x * bv.y; acc[0][2] += av.x * bv.z; acc[0][3] += av.x * bv.w;
            acc[1][0] += av.y * bv.x; acc[1][1] += av.y * bv.y; acc[1][2] += av.y * bv.z; acc[1][3] += av.y * bv.w;
            acc[2][0] += av.z * bv.x; acc[2][1] += av.z * bv.y; acc[2][2] += av.z * bv.z; acc[2][3] += av.z * bv.w;
            acc[3][0] += av.w * bv.x; acc[3][1] += av.w * bv.y; acc[3][2] += av.w * bv.z; acc[3][3] += av.w * bv.w;
        }
        __syncthreads();
    }
    float* dst = attn + ((size_t)b * 2048 + oy * 64 + ty * 4) * 2048 + ix * 64 + tx * 4;
#pragma unroll
    for (int i = 0; i < 4; ++i)
        *(float4*)(dst + (size_t)i * 2048) = make_float4(acc[i][0], acc[i][1], acc[i][2], acc[i][3]);
}

__global__ __launch_bounds__(256) void pv_f32(
    const float* __restrict__ attn, const float* __restrict__ ctx,
    float* __restrict__ mix)
{
    __shared__ float As[BK][PAD];
    __shared__ float Bs[BK][PAD];
    const int b = blockIdx.z, my = blockIdx.y, nx = blockIdx.x;
    const int tid = threadIdx.x;
    const int tx = tid & 15, ty = tid >> 4;
    const float* Abase = attn + ((size_t)b * 2048 + my * 64) * 2048;
    const float* Bbase = ctx  + ((size_t)b * 2048) * 512 + nx * 64;
    float acc[4][4] = {};
    for (int kk = 0; kk < 2048; kk += BK) {
#pragma unroll
        for (int h = 0; h < 2; ++h) {
            const int f = tid + h * 256;
            const int row = f >> 3, k4 = f & 7;
            float4 a = *(const float4*)(Abase + (size_t)row * 2048 + kk + k4 * 4);
            As[k4 * 4 + 0][row] = a.x; As[k4 * 4 + 1][row] = a.y;
            As[k4 * 4 + 2][row] = a.z; As[k4 * 4 + 3][row] = a.w;
            const int krow = f >> 4, col4 = f & 15;
            float4 c = *(const float4*)(Bbase + (size_t)(kk + krow) * 512 + col4 * 4);
            *(float4*)&Bs[krow][col4 * 4] = c;
        }
        __syncthreads();
#pragma unroll
        for (int k = 0; k < BK; ++k) {
            float4 av = *(const float4*)&As[k][ty * 4];
            float4 bv = *(const float4*)&Bs[k][tx * 4];
            acc[0][0] += av.x * bv.x; acc[0][1] += av.x * bv.y; acc[0][2] += av.x * bv.z; acc[0][3] += av.x * bv.w;
            acc[1][0] += av.y * bv.x; acc[1][1] += av.y * bv.y; acc[1][2] += av.y * bv.z; acc[1][3] += av.y * bv.w;
            acc[2][0] += av.z * bv.x; acc[2][1] += av.z * bv.y; acc[2][2] += av.z * bv.z; acc[2][3] += av.z * bv.w;
            acc[3][0] += av.w * bv.x; acc[3][1] += av.w * bv.y; acc[3][2] += av.w * bv.z; acc[3][3] += av.w * bv.w;
        }
        __syncthreads();
    }
    float* dst = mix + ((size_t)b * 2048 + my * 64 + ty * 4) * 512 + nx * 64 + tx * 4;
#pragma unroll
    for (int i = 0; i < 4; ++i)
        *(float4*)(dst + (size_t)i * 512) = make_float4(acc[i][0], acc[i][1], acc[i][2], acc[i][3]);
}

__global__ __launch_bounds__(256) void linear_f32(
    const float* __restrict__ mix, const float* __restrict__ outp,
    const float* __restrict__ Wm, const float* __restrict__ bias,
    float* __restrict__ dst)
{
    __shared__ float As[BK][PAD];
    __shared__ float Ws[BK][PAD];
    const int my = blockIdx.y, nx = blockIdx.x;
    const int tid = threadIdx.x;
    const int tx = tid & 15, ty = tid >> 4;
    const int m0 = my * 64, n0 = nx * 64;
    float acc[4][4] = {};
    for (int kk = 0; kk < 1024; kk += BK) {
        const float* Abase = (kk < 512) ? (mix + (size_t)m0 * 512 + kk)
                                        : (outp + (size_t)m0 * 512 + (kk - 512));
#pragma unroll
        for (int h = 0; h < 2; ++h) {
            const int f = tid + h * 256;
            const int row = f >> 3, k4 = f & 7;
            float4 a = *(const float4*)(Abase + (size_t)row * 512 + k4 * 4);
            As[k4 * 4 + 0][row] = a.x; As[k4 * 4 + 1][row] = a.y;
            As[k4 * 4 + 2][row] = a.z; As[k4 * 4 + 3][row] = a.w;
            float4 w = *(const float4*)(Wm + (size_t)(n0 + row) * 1024 + kk + k4 * 4);
            Ws[k4 * 4 + 0][row] = w.x; Ws[k4 * 4 + 1][row] = w.y;
            Ws[k4 * 4 + 2][row] = w.z; Ws[k4 * 4 + 3][row] = w.w;
        }
        __syncthreads();
#pragma unroll
        for (int k = 0; k < BK; ++k) {
            float4 av = *(const float4*)&As[k][ty * 4];
            float4 bv = *(const float4*)&Ws[k][tx * 4];
            acc[0][0] += av.x * bv.x; acc[0][1] += av.x * bv.y; acc[0][2] += av.x * bv.z; acc[0][3] += av.x * bv.w;
            acc[1][0] += av.y * bv.x; acc[1][1] += av.y * bv.y; acc[1][2] += av.y * bv.z; acc[1][3] += av.y * bv.w;
            acc[2][0] += av.z * bv.x; acc[2][1] += av.z * bv.y; acc[2][2] += av.z * bv.z; acc[2][3] += av.z * bv.w;
            acc[3][0] += av.w * bv.x; acc[3][1] += av.w * bv.y; acc[3][2] += av.w * bv.z; acc[3][3] += av.w * bv.w;
        }
        __syncthreads();
    }
#pragma unroll
    for (int i = 0; i < 4; ++i) {
        const int n = n0 + tx * 4;
        float4 bv = *(const float4*)(bias + n);
        float4 v;
        v.x = tanhf(acc[i][0] + bv.x); v.y = tanhf(acc[i][1] + bv.y);
        v.z = tanhf(acc[i][2] + bv.z); v.w = tanhf(acc[i][3] + bv.w);
        *(float4*)(dst + (size_t)(m0 + ty * 4 + i) * 512 + n) = v;
    }
}

// ===========================================================================
extern "C" void kernel_launch(void* const* d_in, const int* in_sizes, int n_in,
                              void* d_out, int out_size, void* d_ws, size_t ws_size,
                              hipStream_t stream) {
    const float* outp = (const float*)d_in[0];   // [8,2048,512]
    const float* ctx  = (const float*)d_in[1];   // [8,2048,512]
    const float* Wm   = (const float*)d_in[2];   // [512,1024]
    const float* bias = (const float*)d_in[3];   // [512]

    float* out  = (float*)d_out;
    float* attn = out + (size_t)8 * 2048 * 512;

    const size_t MB = 1ull << 20;
    const size_t NEED1 = 162 * MB;   // tier-1: +64MB attn_bf, mix aliases ctx
    const size_t NEED2 = 130 * MB;   // tier-2: round-1 layout

    if (ws_size >= NEED1) {
        char* w = (char*)d_ws;
        unsigned short* outp_hi = (unsigned short*)(w);              // 16MB
        unsigned short* outp_lo = (unsigned short*)(w + 16 * MB);
        unsigned short* ctx_hi  = (unsigned short*)(w + 32 * MB);
        unsigned short* ctx_lo  = (unsigned short*)(w + 48 * MB);
        unsigned short* ctxT_hi = (unsigned short*)(w + 64 * MB);
        unsigned short* ctxT_lo = (unsigned short*)(w + 80 * MB);
        unsigned short* W_hi    = (unsigned short*)(w + 96 * MB);
        unsigned short* W_lo    = (unsigned short*)(w + 97 * MB);
        unsigned short* attn_bf = (unsigned short*)(w + 98 * MB);    // 64MB
        // mix aliases ctx_hi/ctx_lo (ctx dead after scores)
        unsigned short* mix_hi  = ctx_hi;
        unsigned short* mix_lo  = ctx_lo;

        split_kernel<<<dim3(8192), 256, 0, stream>>>(outp, outp_hi, outp_lo);
        split_kernel<<<dim3(8192), 256, 0, stream>>>(ctx, ctx_hi, ctx_lo);
        split_kernel<<<dim3(512), 256, 0, stream>>>(Wm, W_hi, W_lo);
        transpose_split_kernel<<<dim3(16, 64, 8), 256, 0, stream>>>(ctx, ctxT_hi, ctxT_lo);

        scores_mfma8<<<dim3(512), 512, 0, stream>>>(outp_hi, outp_lo, ctx_hi, ctx_lo, attn);
        softmax_kernel<<<dim3(16384), 256, 0, stream>>>(attn, attn_bf);
        pv_mfma8<<<dim3(256), 512, 0, stream>>>(attn_bf, ctxT_hi, ctxT_lo, mix_hi, mix_lo);
        linear_mfma8<<<dim3(256), 512, 0, stream>>>(mix_hi, mix_lo, outp_hi, outp_lo,
                                                    W_hi, W_lo, bias, out);
    } else if (ws_size >= NEED2) {
        char* w = (char*)d_ws;
        unsigned short* outp_hi = (unsigned short*)(w);
        unsigned short* outp_lo = (unsigned short*)(w + 16 * MB);
        unsigned short* ctx_hi  = (unsigned short*)(w + 32 * MB);
        unsigned short* ctx_lo  = (unsigned short*)(w + 48 * MB);
        unsigned short* ctxT_hi = (unsigned short*)(w + 64 * MB);
        unsigned short* ctxT_lo = (unsigned short*)(w + 80 * MB);
        unsigned short* W_hi    = (unsigned short*)(w + 96 * MB);
        unsigned short* W_lo    = (unsigned short*)(w + 97 * MB);
        unsigned short* mix_hi  = (unsigned short*)(w + 98 * MB);
        unsigned short* mix_lo  = (unsigned short*)(w + 114 * MB);

        split_kernel<<<dim3(8192), 256, 0, stream>>>(outp, outp_hi, outp_lo);
        split_kernel<<<dim3(8192), 256, 0, stream>>>(ctx, ctx_hi, ctx_lo);
        split_kernel<<<dim3(512), 256, 0, stream>>>(Wm, W_hi, W_lo);
        transpose_split_kernel<<<dim3(16, 64, 8), 256, 0, stream>>>(ctx, ctxT_hi, ctxT_lo);

        scores_mfma8<<<dim3(512), 512, 0, stream>>>(outp_hi, outp_lo, ctx_hi, ctx_lo, attn);
        softmax_kernel<<<dim3(16384), 256, 0, stream>>>(attn, nullptr);
        pv_mfma_cvt<<<dim3(512), 256, 0, stream>>>(attn, ctxT_hi, ctxT_lo, mix_hi, mix_lo);
        linear_mfma8<<<dim3(256), 512, 0, stream>>>(mix_hi, mix_lo, outp_hi, outp_lo,
                                                    W_hi, W_lo, bias, out);
    } else {
        float* mix = (float*)d_ws;
        scores_f32<<<dim3(32, 32, 8), 256, 0, stream>>>(outp, ctx, attn);
        softmax_kernel<<<dim3(16384), 256, 0, stream>>>(attn, nullptr);
        pv_f32<<<dim3(8, 32, 8), 256, 0, stream>>>(attn, ctx, mix);
        linear_f32<<<dim3(8, 256), 256, 0, stream>>>(mix, outp, Wm, bias, out);
    }
}